// Round 2
// baseline (51039.130 us; speedup 1.0000x reference)
//
#include <hip/hip_runtime.h>

#define T_STEPS 32768
#define OUT_BASE 9830400  // 32768*300

typedef _Float16 h2 __attribute__((ext_vector_type(2)));

#define H2BC(f_) __builtin_bit_cast(h2, f_)

__device__ __forceinline__ float fdot2(h2 a, h2 b, float c) {
#if __has_builtin(__builtin_amdgcn_fdot2)
    return __builtin_amdgcn_fdot2(a, b, c, false);
#else
    return c + (float)a.x * (float)b.x + (float)a.y * (float)b.y;
#endif
}

__device__ __forceinline__ float sigf(float x) { return 1.f / (1.f + __expf(-x)); }

__device__ __forceinline__ float tanh_f(float x) {
    float a = fabsf(x);
    float e = __expf(-2.f * a);
    float t = (1.f - e) / (1.f + e);
    return x < 0.f ? -t : t;
}

// quad_perm DPP cross-lane read (VALU speed, no LDS). CTRL: 0xB1=xor1, 0x4E=xor2, 0x1B=xor3.
template <int CTRL>
__device__ __forceinline__ float qperm(float x) {
#if __has_builtin(__builtin_amdgcn_update_dpp)
    return __builtin_bit_cast(
        float, __builtin_amdgcn_update_dpp(0, __builtin_bit_cast(int, x), CTRL, 0xF, 0xF, true));
#else
    return __shfl_xor(x, CTRL == 0xB1 ? 1 : (CTRL == 0x4E ? 2 : 3));
#endif
}

// Barrier that drains ONLY LDS (lgkmcnt). __syncthreads() would emit
// s_waitcnt vmcnt(0) before s_barrier, serializing the x0p prefetch /
// h1s store latency into every tick.
__device__ __forceinline__ void bar_lds() {
    asm volatile("s_waitcnt lgkmcnt(0)\n\ts_barrier" ::: "memory");
}

// ---------------- A0: Wc = W_ih_l0 @ W_inp  [400x300]; bc = W_ih_l0@b_inp + b_ih0 + b_hh0 ----------------
__global__ void k_precomp(const float* __restrict__ W_inp, const float* __restrict__ b_inp,
                          const float* __restrict__ W_ih0, const float* __restrict__ b_ih0,
                          const float* __restrict__ b_hh0,
                          float* __restrict__ Wc, float* __restrict__ bc) {
    int idx = blockIdx.x * 256 + threadIdx.x;
    if (idx < 120000) {
        int r = idx / 300, d = idx % 300;
        float acc = 0.f;
        for (int h = 0; h < 100; h++) acc += W_ih0[r * 100 + h] * W_inp[h * 300 + d];
        Wc[idx] = acc;
    } else if (idx < 120400) {
        int r = idx - 120000;
        float acc = b_ih0[r] + b_hh0[r];
        for (int h = 0; h < 100; h++) acc += W_ih0[r * 100 + h] * b_inp[h];
        bc[r] = acc;
    }
}

// ---------------- A1: x0p[t][perm(r)] = inputs[t] . Wc[r] + bc[r], stored f16 ----------------
// perm(r) = (r%100)*4 + r/100: k_scan pair p (= j>>1) with gate g=p&3, unit u=p>>2
// (row r = g*100+u) reads x0p[t*400 + p] with unit stride over pairs.
__global__ __launch_bounds__(512) void k_xproj(const float* __restrict__ inp,
                                               const float* __restrict__ Wc,
                                               const float* __restrict__ bc,
                                               _Float16* __restrict__ x0p) {
    __shared__ float xs[32 * 300];
    int t0 = blockIdx.x * 32;
    for (int idx = threadIdx.x; idx < 9600; idx += 512) xs[idx] = inp[(size_t)t0 * 300 + idx];
    __syncthreads();
    int j = threadIdx.x;
    if (j < 400) {
        float acc[32];
#pragma unroll
        for (int i = 0; i < 32; i++) acc[i] = 0.f;
        const float4* w4 = (const float4*)(Wc + j * 300);
        const float4* x4 = (const float4*)xs;
        for (int d4 = 0; d4 < 75; d4++) {
            float4 w = w4[d4];
#pragma unroll
            for (int ti = 0; ti < 32; ti++) {
                float4 x = x4[ti * 75 + d4];
                acc[ti] += w.x * x.x + w.y * x.y + w.z * x.z + w.w * x.w;
            }
        }
        float bb = bc[j];
        int dst = (j % 100) * 4 + j / 100;
#pragma unroll
        for (int ti = 0; ti < 32; ti++)
            x0p[(size_t)(t0 + ti) * 400 + dst] = (_Float16)(acc[ti] + bb);
    }
}

// One tick, pair-split rows. Thread j: half (j&1) of gate g=(j>>1)&3, unit u=j>>3,
// for BOTH layers (row r = g*100+u). Halves: l0 splits h0 at col 48 (uniform 26-h2
// reads, half0's last 2 weights zeroed); l1 splits as half0=W_ih1·h0, half1=W_hh1·h1.
// hbuf layout (f16): h0 at [0..99], h1 at [104..203] (8B pad keeps both halves'
// float4 reads 16B-aligned). Combine halves: one quad_perm xor1 add. Gate gather:
// own=i(lane 8u+0), f via qperm xor2, g via shfl_xor 4, o via qperm xor2 of that.
// ONE barrier per tick (read hbuf[P_], write hbuf[1-P_]).
#define TICK(T_, XREG_, TNEXT_, P_) do {                                                     \
    if (j < 800) {                                                                           \
        float xc_ = XREG_;                                                                   \
        int tn_ = (TNEXT_) < T_STEPS ? (TNEXT_) : T_STEPS - 1;                               \
        XREG_ = (float)x0p[(size_t)tn_ * 400 + (j >> 1)];                                    \
        const char* hb_ = (const char*)hbuf[P_];                                             \
        const float4* u0_ = (const float4*)(hb_ + b0off);                                    \
        const float4* u1_ = (const float4*)(hb_ + b1off);                                    \
        float a0a_ = half ? 0.f : xc_, a0b_ = 0.f;                                           \
        float a1a_ = b1c, a1b_ = 0.f, a1c_ = 0.f, a1d_ = 0.f;                                \
        _Pragma("unroll")                                                                    \
        for (int c_ = 0; c_ < 6; c_++) {                                                     \
            float4 v_ = u0_[c_];                                                             \
            a0a_ = fdot2(w0h[4 * c_ + 0], H2BC(v_.x), a0a_);                                 \
            a0b_ = fdot2(w0h[4 * c_ + 1], H2BC(v_.y), a0b_);                                 \
            a0a_ = fdot2(w0h[4 * c_ + 2], H2BC(v_.z), a0a_);                                 \
            a0b_ = fdot2(w0h[4 * c_ + 3], H2BC(v_.w), a0b_);                                 \
        }                                                                                    \
        { float2 v_ = *(const float2*)(hb_ + b0off + 96);                                    \
          a0a_ = fdot2(w0h[24], H2BC(v_.x), a0a_);                                           \
          a0b_ = fdot2(w0h[25], H2BC(v_.y), a0b_); }                                         \
        _Pragma("unroll")                                                                    \
        for (int c_ = 0; c_ < 12; c_++) {                                                    \
            float4 v_ = u1_[c_];                                                             \
            a1a_ = fdot2(w1h[4 * c_ + 0], H2BC(v_.x), a1a_);                                 \
            a1b_ = fdot2(w1h[4 * c_ + 1], H2BC(v_.y), a1b_);                                 \
            a1c_ = fdot2(w1h[4 * c_ + 2], H2BC(v_.z), a1c_);                                 \
            a1d_ = fdot2(w1h[4 * c_ + 3], H2BC(v_.w), a1d_);                                 \
        }                                                                                    \
        { float2 v_ = *(const float2*)(hb_ + b1off + 192);                                   \
          a1a_ = fdot2(w1h[48], H2BC(v_.x), a1a_);                                           \
          a1b_ = fdot2(w1h[49], H2BC(v_.y), a1b_); }                                         \
        float s0_ = a0a_ + a0b_;  s0_ += qperm<0xB1>(s0_);                                   \
        float s1_ = (a1a_ + a1b_) + (a1c_ + a1d_);  s1_ += qperm<0xB1>(s1_);                 \
        float nl0_ = __builtin_fmaf(sigf(s0_ * s_), s_, addc_);                              \
        float nl1_ = __builtin_fmaf(sigf(s1_ * s_), s_, addc_);                              \
        float y0_ = __shfl_xor(nl0_, 4);                                                     \
        float y1_ = __shfl_xor(nl1_, 4);                                                     \
        float fg0_ = qperm<0x4E>(nl0_), og0_ = qperm<0x4E>(y0_);                             \
        float fg1_ = qperm<0x4E>(nl1_), og1_ = qperm<0x4E>(y1_);                             \
        if ((j & 7) == 0) {                                                                  \
            int u_ = j >> 3;                                                                 \
            _Float16* hw_ = hbuf[1 - (P_)];                                                  \
            c0 = fg0_ * c0 + nl0_ * y0_;                                                     \
            float h0v_ = og0_ * tanh_f(c0);                                                  \
            hw_[u_] = (_Float16)h0v_;                                                        \
            if ((T_) >= 1) {                                                                 \
                c1 = fg1_ * c1 + nl1_ * y1_;                                                 \
                float h1v_ = og1_ * tanh_f(c1);                                              \
                hw_[104 + u_] = (_Float16)h1v_;                                              \
                h1s[(size_t)((T_) - 1) * 100 + u_] = h1v_;                                   \
            }                                                                                \
            if ((T_) == T_STEPS - 1) { outTail[u_] = h0v_; outTail[200 + u_] = c0; }         \
        }                                                                                    \
    }                                                                                        \
    bar_lds();                                                                               \
} while (0)

// ---------------- Scan: single block, 832 threads (800 active = 13 waves), layer1 lags 1 tick --------
// __launch_bounds__(832, 4): 4 waves/EU -> 128-VGPR cap; per-thread demand is
// ~76 weight h2 regs + working set, so everything stays in arch VGPRs (no AGPR
// copies, no scratch).
__global__ __launch_bounds__(832, 4)
void k_scan(const _Float16* __restrict__ x0p,
            const float* __restrict__ Whh0,
            const float* __restrict__ Wih1,
            const float* __restrict__ Whh1,
            const float* __restrict__ bih1,
            const float* __restrict__ bhh1,
            float* __restrict__ h1s,
            float* __restrict__ outTail) {
    // double-buffered f16 hidden state, padded: [b][0..99]=h0, [b][104..203]=h1
    __shared__ __align__(16) _Float16 hbuf[2][208];
    const int j = threadIdx.x;
    const int half = j & 1;
    const int g = (j >> 1) & 3;

    h2 w0h[26];  // half of W_hh_l0 row r (l0 split at col 48; half0's [24],[25]=0)
    h2 w1h[50];  // half0: W_ih_l1 row r; half1: W_hh_l1 row r
    float b1c = 0.f, xa = 0.f, xb = 0.f;
    if (j < 800) {
        int r = g * 100 + (j >> 3);  // gate-major row
        const float2* q0 = (const float2*)(Whh0 + r * 100) + half * 24;
#pragma unroll
        for (int k = 0; k < 26; k++) { float2 v = q0[k]; h2 q; q.x = (_Float16)v.x; q.y = (_Float16)v.y; w0h[k] = q; }
        if (!half) { h2 z; z.x = (_Float16)0.f; z.y = (_Float16)0.f; w0h[24] = z; w0h[25] = z; }
        const float2* q1 = (const float2*)((half ? Whh1 : Wih1) + r * 100);
#pragma unroll
        for (int k = 0; k < 50; k++) { float2 v = q1[k]; h2 q; q.x = (_Float16)v.x; q.y = (_Float16)v.y; w1h[k] = q; }
        if (!half) b1c = bih1[r] + bhh1[r];
        xa = (float)x0p[j >> 1];        // x(0), permuted layout (both halves load; only half0 adds)
        xb = (float)x0p[400 + (j >> 1)];  // x(1)
    }
    if (j < 208) ((unsigned int*)hbuf)[j] = 0u;  // zero both buffers (832 B)
    // branchless gate nonlinearity: lane g==2 computes tanh = 2*sig(2x)-1
    const float s_ = (g == 2) ? 2.f : 1.f;
    const float addc_ = (g == 2) ? -1.f : 0.f;
    const int b0off = half * 96;   // l0 input bytes: [0,104) / [96,200)
    const int b1off = half * 208;  // l1 input bytes: [0,200)=h0 / [208,408)=h1
    float c0 = 0.f, c1 = 0.f;
    __syncthreads();

    for (int t = 0; t < T_STEPS; t += 2) {
        TICK(t, xa, t + 2, 0);      // read hbuf[0], write hbuf[1]; prefetch x(t+2)
        TICK(t + 1, xb, t + 3, 1);  // read hbuf[1], write hbuf[0]; prefetch x(t+3)
    }

    // Drain tick (t == T_STEPS): gates1 for step T-1 from hbuf[0] = {h0(T-1), h1(T-2)}.
    if (j < 800) {
        const char* hb_ = (const char*)hbuf[0];
        const float4* u1_ = (const float4*)(hb_ + b1off);
        float a1a_ = b1c, a1b_ = 0.f, a1c_ = 0.f, a1d_ = 0.f;
#pragma unroll
        for (int c_ = 0; c_ < 12; c_++) {
            float4 v_ = u1_[c_];
            a1a_ = fdot2(w1h[4 * c_ + 0], H2BC(v_.x), a1a_);
            a1b_ = fdot2(w1h[4 * c_ + 1], H2BC(v_.y), a1b_);
            a1c_ = fdot2(w1h[4 * c_ + 2], H2BC(v_.z), a1c_);
            a1d_ = fdot2(w1h[4 * c_ + 3], H2BC(v_.w), a1d_);
        }
        { float2 v_ = *(const float2*)(hb_ + b1off + 192);
          a1a_ = fdot2(w1h[48], H2BC(v_.x), a1a_);
          a1b_ = fdot2(w1h[49], H2BC(v_.y), a1b_); }
        float s1_ = (a1a_ + a1b_) + (a1c_ + a1d_);  s1_ += qperm<0xB1>(s1_);
        float nl1_ = __builtin_fmaf(sigf(s1_ * s_), s_, addc_);
        float y1_ = __shfl_xor(nl1_, 4);
        float fg1_ = qperm<0x4E>(nl1_), og1_ = qperm<0x4E>(y1_);
        if ((j & 7) == 0) {
            int u_ = j >> 3;
            c1 = fg1_ * c1 + nl1_ * y1_;
            float h1v_ = og1_ * tanh_f(c1);
            h1s[(size_t)(T_STEPS - 1) * 100 + u_] = h1v_;
            outTail[100 + u_] = h1v_;
            outTail[300 + u_] = c1;
        }
    }
}

// ---------------- C: outputs[t][d] = h1s[t] . W_out[d] + b_out[d] ----------------
__global__ __launch_bounds__(320) void k_out(const float* __restrict__ h1s,
                                             const float* __restrict__ Wout,
                                             const float* __restrict__ bout,
                                             float* __restrict__ out) {
    __shared__ float hs[32 * 100];
    int t0 = blockIdx.x * 32;
    for (int idx = threadIdx.x; idx < 3200; idx += 320) hs[idx] = h1s[(size_t)t0 * 100 + idx];
    __syncthreads();
    int d = threadIdx.x;
    if (d < 300) {
        float acc[32];
#pragma unroll
        for (int i = 0; i < 32; i++) acc[i] = 0.f;
        const float4* w4 = (const float4*)(Wout + d * 100);
        const float4* h4 = (const float4*)hs;
        for (int j4 = 0; j4 < 25; j4++) {
            float4 w = w4[j4];
#pragma unroll
            for (int ti = 0; ti < 32; ti++) {
                float4 h = h4[ti * 25 + j4];
                acc[ti] += w.x * h.x + w.y * h.y + w.z * h.z + w.w * h.w;
            }
        }
        float bb = bout[d];
#pragma unroll
        for (int ti = 0; ti < 32; ti++) out[(size_t)(t0 + ti) * 300 + d] = acc[ti] + bb;
    }
}

extern "C" void kernel_launch(void* const* d_in, const int* in_sizes, int n_in,
                              void* d_out, int out_size, void* d_ws, size_t ws_size,
                              hipStream_t stream) {
    const float* inputs = (const float*)d_in[0];
    const float* W_inp  = (const float*)d_in[1];
    const float* b_inp  = (const float*)d_in[2];
    const float* W_ih0  = (const float*)d_in[3];
    const float* W_hh0  = (const float*)d_in[4];
    const float* b_ih0  = (const float*)d_in[5];
    const float* b_hh0  = (const float*)d_in[6];
    const float* W_ih1  = (const float*)d_in[7];
    const float* W_hh1  = (const float*)d_in[8];
    const float* b_ih1  = (const float*)d_in[9];
    const float* b_hh1  = (const float*)d_in[10];
    const float* W_out  = (const float*)d_in[11];
    const float* b_out  = (const float*)d_in[12];
    float* out = (float*)d_out;

    char* ws = (char*)d_ws;
    _Float16* x0p = (_Float16*)ws;                         // 32768*400*2 = 26,214,400 B
    float* h1s = (float*)(ws + 26214400);                  // 32768*100*4 = 13,107,200 B
    float* Wc  = (float*)(ws + 26214400 + 13107200);       // 400*300*4   =    480,000 B
    float* bc  = Wc + 120000;                              // 400*4 B

    k_precomp<<<471, 256, 0, stream>>>(W_inp, b_inp, W_ih0, b_ih0, b_hh0, Wc, bc);
    k_xproj<<<1024, 512, 0, stream>>>(inputs, Wc, bc, x0p);
    k_scan<<<1, 832, 0, stream>>>(x0p, W_hh0, W_ih1, W_hh1, b_ih1, b_hh1, h1s, out + OUT_BASE);
    k_out<<<1024, 320, 0, stream>>>(h1s, W_out, b_out, out);
}

// Round 3
// 50819.702 us; speedup vs baseline: 1.0043x; 1.0043x over previous
//
#include <hip/hip_runtime.h>

#define T_STEPS 32768
#define OUT_BASE 9830400  // 32768*300

typedef _Float16 h2 __attribute__((ext_vector_type(2)));

#define H2BC(f_) __builtin_bit_cast(h2, f_)

__device__ __forceinline__ float fdot2(h2 a, h2 b, float c) {
#if __has_builtin(__builtin_amdgcn_fdot2)
    return __builtin_amdgcn_fdot2(a, b, c, false);
#else
    return c + (float)a.x * (float)b.x + (float)a.y * (float)b.y;
#endif
}

__device__ __forceinline__ float sigf(float x) { return 1.f / (1.f + __expf(-x)); }

__device__ __forceinline__ float tanh_f(float x) {
    float a = fabsf(x);
    float e = __expf(-2.f * a);
    float t = (1.f - e) / (1.f + e);
    return x < 0.f ? -t : t;
}

// DPP cross-lane read (VALU speed, no LDS pipe).
// CTRL: 0xB1=quad xor1, 0x4E=quad xor2, 0x1B=quad xor3, 0x141=row_half_mirror
// (lane i <- lane 7-i within each 8-lane group).
template <int CTRL>
__device__ __forceinline__ float qperm(float x) {
#if __has_builtin(__builtin_amdgcn_update_dpp)
    return __builtin_bit_cast(
        float, __builtin_amdgcn_update_dpp(0, __builtin_bit_cast(int, x), CTRL, 0xF, 0xF, true));
#else
    return __shfl_xor(x, CTRL == 0xB1 ? 1 : (CTRL == 0x4E ? 2 : (CTRL == 0x1B ? 3 : 7)));
#endif
}

// Barrier that drains ONLY LDS (lgkmcnt). __syncthreads() would emit
// s_waitcnt vmcnt(0) before s_barrier, serializing the x0p prefetch /
// h1s store latency into every tick.
__device__ __forceinline__ void bar_lds() {
    asm volatile("s_waitcnt lgkmcnt(0)\n\ts_barrier" ::: "memory");
}

// ---------------- A0: Wc = W_ih_l0 @ W_inp  [400x300]; bc = W_ih_l0@b_inp + b_ih0 + b_hh0 ----------------
__global__ void k_precomp(const float* __restrict__ W_inp, const float* __restrict__ b_inp,
                          const float* __restrict__ W_ih0, const float* __restrict__ b_ih0,
                          const float* __restrict__ b_hh0,
                          float* __restrict__ Wc, float* __restrict__ bc) {
    int idx = blockIdx.x * 256 + threadIdx.x;
    if (idx < 120000) {
        int r = idx / 300, d = idx % 300;
        float acc = 0.f;
        for (int h = 0; h < 100; h++) acc += W_ih0[r * 100 + h] * W_inp[h * 300 + d];
        Wc[idx] = acc;
    } else if (idx < 120400) {
        int r = idx - 120000;
        float acc = b_ih0[r] + b_hh0[r];
        for (int h = 0; h < 100; h++) acc += W_ih0[r * 100 + h] * b_inp[h];
        bc[r] = acc;
    }
}

// ---------------- A1: x0p[t][perm(r)] = inputs[t] . Wc[r] + bc[r], stored f16 ----------------
// perm(r) = (r%100)*4 + r/100: k_scan pair p (= j>>1) with gate g=p&3, unit u=p>>2
// (row r = g*100+u) reads x0p[t*400 + p] with unit stride over pairs.
__global__ __launch_bounds__(512) void k_xproj(const float* __restrict__ inp,
                                               const float* __restrict__ Wc,
                                               const float* __restrict__ bc,
                                               _Float16* __restrict__ x0p) {
    __shared__ float xs[32 * 300];
    int t0 = blockIdx.x * 32;
    for (int idx = threadIdx.x; idx < 9600; idx += 512) xs[idx] = inp[(size_t)t0 * 300 + idx];
    __syncthreads();
    int j = threadIdx.x;
    if (j < 400) {
        float acc[32];
#pragma unroll
        for (int i = 0; i < 32; i++) acc[i] = 0.f;
        const float4* w4 = (const float4*)(Wc + j * 300);
        const float4* x4 = (const float4*)xs;
        for (int d4 = 0; d4 < 75; d4++) {
            float4 w = w4[d4];
#pragma unroll
            for (int ti = 0; ti < 32; ti++) {
                float4 x = x4[ti * 75 + d4];
                acc[ti] += w.x * x.x + w.y * x.y + w.z * x.z + w.w * x.w;
            }
        }
        float bb = bc[j];
        int dst = (j % 100) * 4 + j / 100;
#pragma unroll
        for (int ti = 0; ti < 32; ti++)
            x0p[(size_t)(t0 + ti) * 400 + dst] = (_Float16)(acc[ti] + bb);
    }
}

// One tick, pair-split rows. Thread j: half (j&1) of gate g=(j>>1)&3, unit u=j>>3,
// for BOTH layers (row r = g*100+u). Halves: l0 splits h0 at col 48 (uniform 26-h2
// reads, half0's last 2 weights zeroed); l1 splits as half0=W_ih1·h0, half1=W_hh1·h1.
// hbuf layout (f16): h0 at [0..99], h1 at [104..203] (8B pad keeps both halves'
// float4 reads 16B-aligned). Combine halves: quad_perm xor1 add. Gate gather is
// pure DPP within each 8-lane group (leader = lane 8u):
//   i = own nl; f = quad_perm xor2 (lane 2); o = row_half_mirror (lane 7);
//   g = row_half_mirror of quad_perm xor3 (lane 7^3 = 4).
// ONE barrier per tick (read hbuf[P_], write hbuf[1-P_]).
#define TICK(T_, XREG_, TNEXT_, P_) do {                                                     \
    if (j < 800) {                                                                           \
        float xc_ = XREG_;                                                                   \
        int tn_ = (TNEXT_) < T_STEPS ? (TNEXT_) : T_STEPS - 1;                               \
        XREG_ = (float)x0p[(size_t)tn_ * 400 + (j >> 1)];                                    \
        const char* hb_ = (const char*)hbuf[P_];                                             \
        const float4* u0_ = (const float4*)(hb_ + b0off);                                    \
        const float4* u1_ = (const float4*)(hb_ + b1off);                                    \
        float a0a_ = half ? 0.f : xc_, a0b_ = 0.f;                                           \
        float a1a_ = b1c, a1b_ = 0.f, a1c_ = 0.f, a1d_ = 0.f;                                \
        _Pragma("unroll")                                                                    \
        for (int c_ = 0; c_ < 6; c_++) {                                                     \
            float4 v_ = u0_[c_];                                                             \
            a0a_ = fdot2(w0h[4 * c_ + 0], H2BC(v_.x), a0a_);                                 \
            a0b_ = fdot2(w0h[4 * c_ + 1], H2BC(v_.y), a0b_);                                 \
            a0a_ = fdot2(w0h[4 * c_ + 2], H2BC(v_.z), a0a_);                                 \
            a0b_ = fdot2(w0h[4 * c_ + 3], H2BC(v_.w), a0b_);                                 \
        }                                                                                    \
        { float2 v_ = *(const float2*)(hb_ + b0off + 96);                                    \
          a0a_ = fdot2(w0h[24], H2BC(v_.x), a0a_);                                           \
          a0b_ = fdot2(w0h[25], H2BC(v_.y), a0b_); }                                         \
        _Pragma("unroll")                                                                    \
        for (int c_ = 0; c_ < 12; c_++) {                                                    \
            float4 v_ = u1_[c_];                                                             \
            a1a_ = fdot2(w1h[4 * c_ + 0], H2BC(v_.x), a1a_);                                 \
            a1b_ = fdot2(w1h[4 * c_ + 1], H2BC(v_.y), a1b_);                                 \
            a1c_ = fdot2(w1h[4 * c_ + 2], H2BC(v_.z), a1c_);                                 \
            a1d_ = fdot2(w1h[4 * c_ + 3], H2BC(v_.w), a1d_);                                 \
        }                                                                                    \
        { float2 v_ = *(const float2*)(hb_ + b1off + 192);                                   \
          a1a_ = fdot2(w1h[48], H2BC(v_.x), a1a_);                                           \
          a1b_ = fdot2(w1h[49], H2BC(v_.y), a1b_); }                                         \
        float s0_ = a0a_ + a0b_;  s0_ += qperm<0xB1>(s0_);                                   \
        float s1_ = (a1a_ + a1b_) + (a1c_ + a1d_);  s1_ += qperm<0xB1>(s1_);                 \
        float nl0_ = __builtin_fmaf(sigf(s0_ * s_), s_, addc_);                              \
        float nl1_ = __builtin_fmaf(sigf(s1_ * s_), s_, addc_);                              \
        float fg0_ = qperm<0x4E>(nl0_);                                                      \
        float og0_ = qperm<0x141>(nl0_);                                                     \
        float gg0_ = qperm<0x141>(qperm<0x1B>(nl0_));                                        \
        float fg1_ = qperm<0x4E>(nl1_);                                                      \
        float og1_ = qperm<0x141>(nl1_);                                                     \
        float gg1_ = qperm<0x141>(qperm<0x1B>(nl1_));                                        \
        if ((j & 7) == 0) {                                                                  \
            int u_ = j >> 3;                                                                 \
            _Float16* hw_ = hbuf[1 - (P_)];                                                  \
            c0 = fg0_ * c0 + nl0_ * gg0_;                                                    \
            float h0v_ = og0_ * tanh_f(c0);                                                  \
            hw_[u_] = (_Float16)h0v_;                                                        \
            if ((T_) >= 1) {                                                                 \
                c1 = fg1_ * c1 + nl1_ * gg1_;                                                \
                float h1v_ = og1_ * tanh_f(c1);                                              \
                hw_[104 + u_] = (_Float16)h1v_;                                              \
                h1s[(size_t)((T_) - 1) * 100 + u_] = h1v_;                                   \
            }                                                                                \
            if ((T_) == T_STEPS - 1) { outTail[u_] = h0v_; outTail[200 + u_] = c0; }         \
        }                                                                                    \
    }                                                                                        \
    bar_lds();                                                                               \
} while (0)

// ---------------- Scan: single block, 832 threads (800 active = 13 waves), layer1 lags 1 tick --------
// amdgpu_waves_per_eu(4,4): pin 4 waves/SIMD -> 128-VGPR cap. (Round 2's
// __launch_bounds__(832,4) allocated for 8 waves/EU -> VGPR_Count=64 -> the
// ~110-reg working set spilled to scratch: 38.6->51 ms. A 13-wave block needs
// VGPR<=128 anyway: the {4,3,3,3} SIMD hosts 4 waves x 128 = full 512-slot file.)
__global__ __launch_bounds__(832) __attribute__((amdgpu_waves_per_eu(4, 4)))
void k_scan(const _Float16* __restrict__ x0p,
            const float* __restrict__ Whh0,
            const float* __restrict__ Wih1,
            const float* __restrict__ Whh1,
            const float* __restrict__ bih1,
            const float* __restrict__ bhh1,
            float* __restrict__ h1s,
            float* __restrict__ outTail) {
    // double-buffered f16 hidden state, padded: [b][0..99]=h0, [b][104..203]=h1
    __shared__ __align__(16) _Float16 hbuf[2][208];
    const int j = threadIdx.x;
    const int half = j & 1;
    const int g = (j >> 1) & 3;

    h2 w0h[26];  // half of W_hh_l0 row r (l0 split at col 48; half0's [24],[25]=0)
    h2 w1h[50];  // half0: W_ih_l1 row r; half1: W_hh_l1 row r
    float b1c = 0.f, xa = 0.f, xb = 0.f;
    if (j < 800) {
        int r = g * 100 + (j >> 3);  // gate-major row
        const float2* q0 = (const float2*)(Whh0 + r * 100) + half * 24;
#pragma unroll
        for (int k = 0; k < 26; k++) { float2 v = q0[k]; h2 q; q.x = (_Float16)v.x; q.y = (_Float16)v.y; w0h[k] = q; }
        if (!half) { h2 z; z.x = (_Float16)0.f; z.y = (_Float16)0.f; w0h[24] = z; w0h[25] = z; }
        const float2* q1 = (const float2*)((half ? Whh1 : Wih1) + r * 100);
#pragma unroll
        for (int k = 0; k < 50; k++) { float2 v = q1[k]; h2 q; q.x = (_Float16)v.x; q.y = (_Float16)v.y; w1h[k] = q; }
        if (!half) b1c = bih1[r] + bhh1[r];
        xa = (float)x0p[j >> 1];          // x(0), permuted layout (both halves load; only half0 adds)
        xb = (float)x0p[400 + (j >> 1)];  // x(1)
    }
    if (j < 208) ((unsigned int*)hbuf)[j] = 0u;  // zero both buffers (832 B)
    // branchless gate nonlinearity: lane g==2 computes tanh = 2*sig(2x)-1
    const float s_ = (g == 2) ? 2.f : 1.f;
    const float addc_ = (g == 2) ? -1.f : 0.f;
    const int b0off = half * 96;   // l0 input bytes: [0,104) / [96,200)
    const int b1off = half * 208;  // l1 input bytes: [0,200)=h0 / [208,408)=h1
    float c0 = 0.f, c1 = 0.f;
    __syncthreads();

    for (int t = 0; t < T_STEPS; t += 2) {
        TICK(t, xa, t + 2, 0);      // read hbuf[0], write hbuf[1]; prefetch x(t+2)
        TICK(t + 1, xb, t + 3, 1);  // read hbuf[1], write hbuf[0]; prefetch x(t+3)
    }

    // Drain tick (t == T_STEPS): gates1 for step T-1 from hbuf[0] = {h0(T-1), h1(T-2)}.
    if (j < 800) {
        const char* hb_ = (const char*)hbuf[0];
        const float4* u1_ = (const float4*)(hb_ + b1off);
        float a1a_ = b1c, a1b_ = 0.f, a1c_ = 0.f, a1d_ = 0.f;
#pragma unroll
        for (int c_ = 0; c_ < 12; c_++) {
            float4 v_ = u1_[c_];
            a1a_ = fdot2(w1h[4 * c_ + 0], H2BC(v_.x), a1a_);
            a1b_ = fdot2(w1h[4 * c_ + 1], H2BC(v_.y), a1b_);
            a1c_ = fdot2(w1h[4 * c_ + 2], H2BC(v_.z), a1c_);
            a1d_ = fdot2(w1h[4 * c_ + 3], H2BC(v_.w), a1d_);
        }
        { float2 v_ = *(const float2*)(hb_ + b1off + 192);
          a1a_ = fdot2(w1h[48], H2BC(v_.x), a1a_);
          a1b_ = fdot2(w1h[49], H2BC(v_.y), a1b_); }
        float s1_ = (a1a_ + a1b_) + (a1c_ + a1d_);  s1_ += qperm<0xB1>(s1_);
        float nl1_ = __builtin_fmaf(sigf(s1_ * s_), s_, addc_);
        float fg1_ = qperm<0x4E>(nl1_);
        float og1_ = qperm<0x141>(nl1_);
        float gg1_ = qperm<0x141>(qperm<0x1B>(nl1_));
        if ((j & 7) == 0) {
            int u_ = j >> 3;
            c1 = fg1_ * c1 + nl1_ * gg1_;
            float h1v_ = og1_ * tanh_f(c1);
            h1s[(size_t)(T_STEPS - 1) * 100 + u_] = h1v_;
            outTail[100 + u_] = h1v_;
            outTail[300 + u_] = c1;
        }
    }
}

// ---------------- C: outputs[t][d] = h1s[t] . W_out[d] + b_out[d] ----------------
__global__ __launch_bounds__(320) void k_out(const float* __restrict__ h1s,
                                             const float* __restrict__ Wout,
                                             const float* __restrict__ bout,
                                             float* __restrict__ out) {
    __shared__ float hs[32 * 100];
    int t0 = blockIdx.x * 32;
    for (int idx = threadIdx.x; idx < 3200; idx += 320) hs[idx] = h1s[(size_t)t0 * 100 + idx];
    __syncthreads();
    int d = threadIdx.x;
    if (d < 300) {
        float acc[32];
#pragma unroll
        for (int i = 0; i < 32; i++) acc[i] = 0.f;
        const float4* w4 = (const float4*)(Wout + d * 100);
        const float4* h4 = (const float4*)hs;
        for (int j4 = 0; j4 < 25; j4++) {
            float4 w = w4[j4];
#pragma unroll
            for (int ti = 0; ti < 32; ti++) {
                float4 h = h4[ti * 25 + j4];
                acc[ti] += w.x * h.x + w.y * h.y + w.z * h.z + w.w * h.w;
            }
        }
        float bb = bout[d];
#pragma unroll
        for (int ti = 0; ti < 32; ti++) out[(size_t)(t0 + ti) * 300 + d] = acc[ti] + bb;
    }
}

extern "C" void kernel_launch(void* const* d_in, const int* in_sizes, int n_in,
                              void* d_out, int out_size, void* d_ws, size_t ws_size,
                              hipStream_t stream) {
    const float* inputs = (const float*)d_in[0];
    const float* W_inp  = (const float*)d_in[1];
    const float* b_inp  = (const float*)d_in[2];
    const float* W_ih0  = (const float*)d_in[3];
    const float* W_hh0  = (const float*)d_in[4];
    const float* b_ih0  = (const float*)d_in[5];
    const float* b_hh0  = (const float*)d_in[6];
    const float* W_ih1  = (const float*)d_in[7];
    const float* W_hh1  = (const float*)d_in[8];
    const float* b_ih1  = (const float*)d_in[9];
    const float* b_hh1  = (const float*)d_in[10];
    const float* W_out  = (const float*)d_in[11];
    const float* b_out  = (const float*)d_in[12];
    float* out = (float*)d_out;

    char* ws = (char*)d_ws;
    _Float16* x0p = (_Float16*)ws;                         // 32768*400*2 = 26,214,400 B
    float* h1s = (float*)(ws + 26214400);                  // 32768*100*4 = 13,107,200 B
    float* Wc  = (float*)(ws + 26214400 + 13107200);       // 400*300*4   =    480,000 B
    float* bc  = Wc + 120000;                              // 400*4 B

    k_precomp<<<471, 256, 0, stream>>>(W_inp, b_inp, W_ih0, b_ih0, b_hh0, Wc, bc);
    k_xproj<<<1024, 512, 0, stream>>>(inputs, Wc, bc, x0p);
    k_scan<<<1, 832, 0, stream>>>(x0p, W_hh0, W_ih1, W_hh1, b_ih1, b_hh1, h1s, out + OUT_BASE);
    k_out<<<1024, 320, 0, stream>>>(h1s, W_out, b_out, out);
}

// Round 4
// 50398.099 us; speedup vs baseline: 1.0127x; 1.0084x over previous
//
#include <hip/hip_runtime.h>

#define T_STEPS 32768
#define OUT_BASE 9830400  // 32768*300

typedef _Float16 h2 __attribute__((ext_vector_type(2)));

#define H2BC(f_) __builtin_bit_cast(h2, f_)

__device__ __forceinline__ float fdot2(h2 a, h2 b, float c) {
#if __has_builtin(__builtin_amdgcn_fdot2)
    return __builtin_amdgcn_fdot2(a, b, c, false);
#else
    return c + (float)a.x * (float)b.x + (float)a.y * (float)b.y;
#endif
}

__device__ __forceinline__ float sigf(float x) { return 1.f / (1.f + __expf(-x)); }

__device__ __forceinline__ float tanh_f(float x) {
    float a = fabsf(x);
    float e = __expf(-2.f * a);
    float t = (1.f - e) / (1.f + e);
    return x < 0.f ? -t : t;
}

// DPP cross-lane read (VALU speed, no LDS pipe).
// CTRL: 0xB1=quad xor1, 0x4E=quad xor2, 0x1B=quad xor3, 0x141=row_half_mirror
// (lane i <- lane 7-i within each 8-lane group).
template <int CTRL>
__device__ __forceinline__ float qperm(float x) {
#if __has_builtin(__builtin_amdgcn_update_dpp)
    return __builtin_bit_cast(
        float, __builtin_amdgcn_update_dpp(0, __builtin_bit_cast(int, x), CTRL, 0xF, 0xF, true));
#else
    return __shfl_xor(x, CTRL == 0xB1 ? 1 : (CTRL == 0x4E ? 2 : (CTRL == 0x1B ? 3 : 7)));
#endif
}

// Barrier that drains ONLY LDS (lgkmcnt). __syncthreads() would emit
// s_waitcnt vmcnt(0) before s_barrier, serializing the x0p prefetch /
// h1s store latency into every tick.
__device__ __forceinline__ void bar_lds() {
    asm volatile("s_waitcnt lgkmcnt(0)\n\ts_barrier" ::: "memory");
}

// ---------------- A0: Wc = W_ih_l0 @ W_inp  [400x300]; bc = W_ih_l0@b_inp + b_ih0 + b_hh0 ----------------
__global__ void k_precomp(const float* __restrict__ W_inp, const float* __restrict__ b_inp,
                          const float* __restrict__ W_ih0, const float* __restrict__ b_ih0,
                          const float* __restrict__ b_hh0,
                          float* __restrict__ Wc, float* __restrict__ bc) {
    int idx = blockIdx.x * 256 + threadIdx.x;
    if (idx < 120000) {
        int r = idx / 300, d = idx % 300;
        float acc = 0.f;
        for (int h = 0; h < 100; h++) acc += W_ih0[r * 100 + h] * W_inp[h * 300 + d];
        Wc[idx] = acc;
    } else if (idx < 120400) {
        int r = idx - 120000;
        float acc = b_ih0[r] + b_hh0[r];
        for (int h = 0; h < 100; h++) acc += W_ih0[r * 100 + h] * b_inp[h];
        bc[r] = acc;
    }
}

// ---------------- A1: x0p[t][perm(r)] = inputs[t] . Wc[r] + bc[r], stored f16 ----------------
// perm(r) = (r%100)*4 + r/100: k_scan pair p (= j>>1) with gate g=p&3, unit u=p>>2
// (row r = g*100+u) reads x0p[t*400 + p] with unit stride over pairs.
__global__ __launch_bounds__(512) void k_xproj(const float* __restrict__ inp,
                                               const float* __restrict__ Wc,
                                               const float* __restrict__ bc,
                                               _Float16* __restrict__ x0p) {
    __shared__ float xs[32 * 300];
    int t0 = blockIdx.x * 32;
    for (int idx = threadIdx.x; idx < 9600; idx += 512) xs[idx] = inp[(size_t)t0 * 300 + idx];
    __syncthreads();
    int j = threadIdx.x;
    if (j < 400) {
        float acc[32];
#pragma unroll
        for (int i = 0; i < 32; i++) acc[i] = 0.f;
        const float4* w4 = (const float4*)(Wc + j * 300);
        const float4* x4 = (const float4*)xs;
        for (int d4 = 0; d4 < 75; d4++) {
            float4 w = w4[d4];
#pragma unroll
            for (int ti = 0; ti < 32; ti++) {
                float4 x = x4[ti * 75 + d4];
                acc[ti] += w.x * x.x + w.y * x.y + w.z * x.z + w.w * x.w;
            }
        }
        float bb = bc[j];
        int dst = (j % 100) * 4 + j / 100;
#pragma unroll
        for (int ti = 0; ti < 32; ti++)
            x0p[(size_t)(t0 + ti) * 400 + dst] = (_Float16)(acc[ti] + bb);
    }
}

// One tick, pair-split rows. Thread j: half (j&1) of gate g=(j>>1)&3, unit u=j>>3,
// for BOTH layers (row r = g*100+u). Halves: l0 splits h0 at col 48 (uniform 26-h2
// reads, half0's last 2 weights zeroed); l1 splits as half0=W_ih1·h0, half1=W_hh1·h1.
// hbuf layout (f16): h0 at [0..99], h1 at [104..203] (8B pad keeps both halves'
// float4 reads 16B-aligned). Combine halves: quad_perm xor1 add. Gate gather is
// pure DPP within each 8-lane group (leader = lane 8u):
//   i = own nl; f = quad_perm xor2 (lane 2); o = row_half_mirror (lane 7);
//   g = row_half_mirror of quad_perm xor3 (lane 7^3 = 4).
// ONE barrier per tick (read hbuf[P_], write hbuf[1-P_]).
#define TICK(T_, XREG_, TNEXT_, P_) do {                                                     \
    if (j < 800) {                                                                           \
        float xc_ = XREG_;                                                                   \
        int tn_ = (TNEXT_) < T_STEPS ? (TNEXT_) : T_STEPS - 1;                               \
        XREG_ = (float)x0p[(size_t)tn_ * 400 + (j >> 1)];                                    \
        const char* hb_ = (const char*)hbuf[P_];                                             \
        const float4* u0_ = (const float4*)(hb_ + b0off);                                    \
        const float4* u1_ = (const float4*)(hb_ + b1off);                                    \
        float a0a_ = half ? 0.f : xc_, a0b_ = 0.f;                                           \
        float a1a_ = b1c, a1b_ = 0.f, a1c_ = 0.f, a1d_ = 0.f;                                \
        _Pragma("unroll")                                                                    \
        for (int c_ = 0; c_ < 6; c_++) {                                                     \
            float4 v_ = u0_[c_];                                                             \
            a0a_ = fdot2(w0h[4 * c_ + 0], H2BC(v_.x), a0a_);                                 \
            a0b_ = fdot2(w0h[4 * c_ + 1], H2BC(v_.y), a0b_);                                 \
            a0a_ = fdot2(w0h[4 * c_ + 2], H2BC(v_.z), a0a_);                                 \
            a0b_ = fdot2(w0h[4 * c_ + 3], H2BC(v_.w), a0b_);                                 \
        }                                                                                    \
        { float2 v_ = *(const float2*)(hb_ + b0off + 96);                                    \
          a0a_ = fdot2(w0h[24], H2BC(v_.x), a0a_);                                           \
          a0b_ = fdot2(w0h[25], H2BC(v_.y), a0b_); }                                         \
        _Pragma("unroll")                                                                    \
        for (int c_ = 0; c_ < 12; c_++) {                                                    \
            float4 v_ = u1_[c_];                                                             \
            a1a_ = fdot2(w1h[4 * c_ + 0], H2BC(v_.x), a1a_);                                 \
            a1b_ = fdot2(w1h[4 * c_ + 1], H2BC(v_.y), a1b_);                                 \
            a1c_ = fdot2(w1h[4 * c_ + 2], H2BC(v_.z), a1c_);                                 \
            a1d_ = fdot2(w1h[4 * c_ + 3], H2BC(v_.w), a1d_);                                 \
        }                                                                                    \
        { float2 v_ = *(const float2*)(hb_ + b1off + 192);                                   \
          a1a_ = fdot2(w1h[48], H2BC(v_.x), a1a_);                                           \
          a1b_ = fdot2(w1h[49], H2BC(v_.y), a1b_); }                                         \
        float s0_ = a0a_ + a0b_;  s0_ += qperm<0xB1>(s0_);                                   \
        float s1_ = (a1a_ + a1b_) + (a1c_ + a1d_);  s1_ += qperm<0xB1>(s1_);                 \
        float nl0_ = __builtin_fmaf(sigf(s0_ * s_), s_, addc_);                              \
        float nl1_ = __builtin_fmaf(sigf(s1_ * s_), s_, addc_);                              \
        float fg0_ = qperm<0x4E>(nl0_);                                                      \
        float og0_ = qperm<0x141>(nl0_);                                                     \
        float gg0_ = qperm<0x141>(qperm<0x1B>(nl0_));                                        \
        float fg1_ = qperm<0x4E>(nl1_);                                                      \
        float og1_ = qperm<0x141>(nl1_);                                                     \
        float gg1_ = qperm<0x141>(qperm<0x1B>(nl1_));                                        \
        if ((j & 7) == 0) {                                                                  \
            int u_ = j >> 3;                                                                 \
            _Float16* hw_ = hbuf[1 - (P_)];                                                  \
            c0 = fg0_ * c0 + nl0_ * gg0_;                                                    \
            float h0v_ = og0_ * tanh_f(c0);                                                  \
            hw_[u_] = (_Float16)h0v_;                                                        \
            if ((T_) >= 1) {                                                                 \
                c1 = fg1_ * c1 + nl1_ * gg1_;                                                \
                float h1v_ = og1_ * tanh_f(c1);                                              \
                hw_[104 + u_] = (_Float16)h1v_;                                              \
                h1s[(size_t)((T_) - 1) * 100 + u_] = h1v_;                                   \
            }                                                                                \
            if ((T_) == T_STEPS - 1) { outTail[u_] = h0v_; outTail[200 + u_] = c0; }         \
        }                                                                                    \
    }                                                                                        \
    bar_lds();                                                                               \
} while (0)

// ---------------- Scan: single block, 832 threads (800 active = 13 waves), layer1 lags 1 tick --------
// amdgpu_waves_per_eu(2, 2): the ONLY empirically-working register pin on this
// kernel family (round 1: VGPR_Count=128). Budget = 512/2 = 256 total; our arch
// demand (~105: 76 weight h2 + temps) fits entirely in arch VGPRs -> agpr_count
// = 0, so each wave's runtime allocation is the 128-slot granule and the 13-wave
// {4,3,3,3} block still fits (4 x 128 = 512-slot file). Rounds 2/3 proved the
// "min waves 4" route (launch_bounds 2nd arg / waves_per_eu(4,4)) pins arch=64
// and spills: 50.7 ms.
__global__ __launch_bounds__(832) __attribute__((amdgpu_waves_per_eu(2, 2)))
void k_scan(const _Float16* __restrict__ x0p,
            const float* __restrict__ Whh0,
            const float* __restrict__ Wih1,
            const float* __restrict__ Whh1,
            const float* __restrict__ bih1,
            const float* __restrict__ bhh1,
            float* __restrict__ h1s,
            float* __restrict__ outTail) {
    // double-buffered f16 hidden state, padded: [b][0..99]=h0, [b][104..203]=h1
    __shared__ __align__(16) _Float16 hbuf[2][208];
    const int j = threadIdx.x;
    const int half = j & 1;
    const int g = (j >> 1) & 3;

    h2 w0h[26];  // half of W_hh_l0 row r (l0 split at col 48; half0's [24],[25]=0)
    h2 w1h[50];  // half0: W_ih_l1 row r; half1: W_hh_l1 row r
    float b1c = 0.f, xa = 0.f, xb = 0.f;
    if (j < 800) {
        int r = g * 100 + (j >> 3);  // gate-major row
        const float2* q0 = (const float2*)(Whh0 + r * 100) + half * 24;
#pragma unroll
        for (int k = 0; k < 26; k++) { float2 v = q0[k]; h2 q; q.x = (_Float16)v.x; q.y = (_Float16)v.y; w0h[k] = q; }
        if (!half) { h2 z; z.x = (_Float16)0.f; z.y = (_Float16)0.f; w0h[24] = z; w0h[25] = z; }
        const float2* q1 = (const float2*)((half ? Whh1 : Wih1) + r * 100);
#pragma unroll
        for (int k = 0; k < 50; k++) { float2 v = q1[k]; h2 q; q.x = (_Float16)v.x; q.y = (_Float16)v.y; w1h[k] = q; }
        if (!half) b1c = bih1[r] + bhh1[r];
        xa = (float)x0p[j >> 1];          // x(0), permuted layout (both halves load; only half0 adds)
        xb = (float)x0p[400 + (j >> 1)];  // x(1)
    }
    if (j < 208) ((unsigned int*)hbuf)[j] = 0u;  // zero both buffers (832 B)
    // branchless gate nonlinearity: lane g==2 computes tanh = 2*sig(2x)-1
    const float s_ = (g == 2) ? 2.f : 1.f;
    const float addc_ = (g == 2) ? -1.f : 0.f;
    const int b0off = half * 96;   // l0 input bytes: [0,104) / [96,200)
    const int b1off = half * 208;  // l1 input bytes: [0,200)=h0 / [208,408)=h1
    float c0 = 0.f, c1 = 0.f;
    __syncthreads();

    for (int t = 0; t < T_STEPS; t += 2) {
        TICK(t, xa, t + 2, 0);      // read hbuf[0], write hbuf[1]; prefetch x(t+2)
        TICK(t + 1, xb, t + 3, 1);  // read hbuf[1], write hbuf[0]; prefetch x(t+3)
    }

    // Drain tick (t == T_STEPS): gates1 for step T-1 from hbuf[0] = {h0(T-1), h1(T-2)}.
    if (j < 800) {
        const char* hb_ = (const char*)hbuf[0];
        const float4* u1_ = (const float4*)(hb_ + b1off);
        float a1a_ = b1c, a1b_ = 0.f, a1c_ = 0.f, a1d_ = 0.f;
#pragma unroll
        for (int c_ = 0; c_ < 12; c_++) {
            float4 v_ = u1_[c_];
            a1a_ = fdot2(w1h[4 * c_ + 0], H2BC(v_.x), a1a_);
            a1b_ = fdot2(w1h[4 * c_ + 1], H2BC(v_.y), a1b_);
            a1c_ = fdot2(w1h[4 * c_ + 2], H2BC(v_.z), a1c_);
            a1d_ = fdot2(w1h[4 * c_ + 3], H2BC(v_.w), a1d_);
        }
        { float2 v_ = *(const float2*)(hb_ + b1off + 192);
          a1a_ = fdot2(w1h[48], H2BC(v_.x), a1a_);
          a1b_ = fdot2(w1h[49], H2BC(v_.y), a1b_); }
        float s1_ = (a1a_ + a1b_) + (a1c_ + a1d_);  s1_ += qperm<0xB1>(s1_);
        float nl1_ = __builtin_fmaf(sigf(s1_ * s_), s_, addc_);
        float fg1_ = qperm<0x4E>(nl1_);
        float og1_ = qperm<0x141>(nl1_);
        float gg1_ = qperm<0x141>(qperm<0x1B>(nl1_));
        if ((j & 7) == 0) {
            int u_ = j >> 3;
            c1 = fg1_ * c1 + nl1_ * gg1_;
            float h1v_ = og1_ * tanh_f(c1);
            h1s[(size_t)(T_STEPS - 1) * 100 + u_] = h1v_;
            outTail[100 + u_] = h1v_;
            outTail[300 + u_] = c1;
        }
    }
}

// ---------------- C: outputs[t][d] = h1s[t] . W_out[d] + b_out[d] ----------------
__global__ __launch_bounds__(320) void k_out(const float* __restrict__ h1s,
                                             const float* __restrict__ Wout,
                                             const float* __restrict__ bout,
                                             float* __restrict__ out) {
    __shared__ float hs[32 * 100];
    int t0 = blockIdx.x * 32;
    for (int idx = threadIdx.x; idx < 3200; idx += 320) hs[idx] = h1s[(size_t)t0 * 100 + idx];
    __syncthreads();
    int d = threadIdx.x;
    if (d < 300) {
        float acc[32];
#pragma unroll
        for (int i = 0; i < 32; i++) acc[i] = 0.f;
        const float4* w4 = (const float4*)(Wout + d * 100);
        const float4* h4 = (const float4*)hs;
        for (int j4 = 0; j4 < 25; j4++) {
            float4 w = w4[j4];
#pragma unroll
            for (int ti = 0; ti < 32; ti++) {
                float4 h = h4[ti * 25 + j4];
                acc[ti] += w.x * h.x + w.y * h.y + w.z * h.z + w.w * h.w;
            }
        }
        float bb = bout[d];
#pragma unroll
        for (int ti = 0; ti < 32; ti++) out[(size_t)(t0 + ti) * 300 + d] = acc[ti] + bb;
    }
}

extern "C" void kernel_launch(void* const* d_in, const int* in_sizes, int n_in,
                              void* d_out, int out_size, void* d_ws, size_t ws_size,
                              hipStream_t stream) {
    const float* inputs = (const float*)d_in[0];
    const float* W_inp  = (const float*)d_in[1];
    const float* b_inp  = (const float*)d_in[2];
    const float* W_ih0  = (const float*)d_in[3];
    const float* W_hh0  = (const float*)d_in[4];
    const float* b_ih0  = (const float*)d_in[5];
    const float* b_hh0  = (const float*)d_in[6];
    const float* W_ih1  = (const float*)d_in[7];
    const float* W_hh1  = (const float*)d_in[8];
    const float* b_ih1  = (const float*)d_in[9];
    const float* b_hh1  = (const float*)d_in[10];
    const float* W_out  = (const float*)d_in[11];
    const float* b_out  = (const float*)d_in[12];
    float* out = (float*)d_out;

    char* ws = (char*)d_ws;
    _Float16* x0p = (_Float16*)ws;                         // 32768*400*2 = 26,214,400 B
    float* h1s = (float*)(ws + 26214400);                  // 32768*100*4 = 13,107,200 B
    float* Wc  = (float*)(ws + 26214400 + 13107200);       // 400*300*4   =    480,000 B
    float* bc  = Wc + 120000;                              // 400*4 B

    k_precomp<<<471, 256, 0, stream>>>(W_inp, b_inp, W_ih0, b_ih0, b_hh0, Wc, bc);
    k_xproj<<<1024, 512, 0, stream>>>(inputs, Wc, bc, x0p);
    k_scan<<<1, 832, 0, stream>>>(x0p, W_hh0, W_ih1, W_hh1, b_ih1, b_hh1, h1s, out + OUT_BASE);
    k_out<<<1024, 320, 0, stream>>>(h1s, W_out, b_out, out);
}

// Round 5
// 25423.299 us; speedup vs baseline: 2.0076x; 1.9824x over previous
//
#include <hip/hip_runtime.h>

#define T_STEPS 32768
#define OUT_BASE 9830400  // 32768*300

typedef _Float16 h2 __attribute__((ext_vector_type(2)));

#define H2BC(f_) __builtin_bit_cast(h2, f_)

__device__ __forceinline__ float fdot2(h2 a, h2 b, float c) {
#if __has_builtin(__builtin_amdgcn_fdot2)
    return __builtin_amdgcn_fdot2(a, b, c, false);
#else
    return c + (float)a.x * (float)b.x + (float)a.y * (float)b.y;
#endif
}

__device__ __forceinline__ float sigf(float x) { return 1.f / (1.f + __expf(-x)); }

__device__ __forceinline__ float tanh_f(float x) {
    float a = fabsf(x);
    float e = __expf(-2.f * a);
    float t = (1.f - e) / (1.f + e);
    return x < 0.f ? -t : t;
}

// quad_perm DPP cross-lane read (VALU speed, no LDS pipe).
// CTRL: 0xB1=xor1, 0x4E=xor2, 0x1B=xor3.
template <int CTRL>
__device__ __forceinline__ float qperm(float x) {
#if __has_builtin(__builtin_amdgcn_update_dpp)
    return __builtin_bit_cast(
        float, __builtin_amdgcn_update_dpp(0, __builtin_bit_cast(int, x), CTRL, 0xF, 0xF, true));
#else
    return __shfl_xor(x, CTRL == 0xB1 ? 1 : (CTRL == 0x4E ? 2 : 3));
#endif
}

// Barrier that drains ONLY LDS (lgkmcnt): keeps helper-wave global loads/stores
// (vmcnt) in flight across the barrier.
__device__ __forceinline__ void bar_lds() {
    asm volatile("s_waitcnt lgkmcnt(0)\n\ts_barrier" ::: "memory");
}

// ---------------- A0: Wc = W_ih_l0 @ W_inp  [400x300]; bc = W_ih_l0@b_inp + b_ih0 + b_hh0 ----------------
__global__ void k_precomp(const float* __restrict__ W_inp, const float* __restrict__ b_inp,
                          const float* __restrict__ W_ih0, const float* __restrict__ b_ih0,
                          const float* __restrict__ b_hh0,
                          float* __restrict__ Wc, float* __restrict__ bc) {
    int idx = blockIdx.x * 256 + threadIdx.x;
    if (idx < 120000) {
        int r = idx / 300, d = idx % 300;
        float acc = 0.f;
        for (int h = 0; h < 100; h++) acc += W_ih0[r * 100 + h] * W_inp[h * 300 + d];
        Wc[idx] = acc;
    } else if (idx < 120400) {
        int r = idx - 120000;
        float acc = b_ih0[r] + b_hh0[r];
        for (int h = 0; h < 100; h++) acc += W_ih0[r * 100 + h] * b_inp[h];
        bc[r] = acc;
    }
}

// ---------------- A1: x0p[t][perm(r)] = inputs[t] . Wc[r] + bc[r], stored f16 ----------------
// perm(r) = (r%100)*4 + r/100: scan thread j (gate g=j&3, unit u=j>>2, row
// r = g*100+u) reads x0p[t*400 + j] with unit stride.
__global__ __launch_bounds__(512) void k_xproj(const float* __restrict__ inp,
                                               const float* __restrict__ Wc,
                                               const float* __restrict__ bc,
                                               _Float16* __restrict__ x0p) {
    __shared__ float xs[32 * 300];
    int t0 = blockIdx.x * 32;
    for (int idx = threadIdx.x; idx < 9600; idx += 512) xs[idx] = inp[(size_t)t0 * 300 + idx];
    __syncthreads();
    int j = threadIdx.x;
    if (j < 400) {
        float acc[32];
#pragma unroll
        for (int i = 0; i < 32; i++) acc[i] = 0.f;
        const float4* w4 = (const float4*)(Wc + j * 300);
        const float4* x4 = (const float4*)xs;
        for (int d4 = 0; d4 < 75; d4++) {
            float4 w = w4[d4];
#pragma unroll
            for (int ti = 0; ti < 32; ti++) {
                float4 x = x4[ti * 75 + d4];
                acc[ti] += w.x * x.x + w.y * x.y + w.z * x.z + w.w * x.w;
            }
        }
        float bb = bc[j];
        int dst = (j % 100) * 4 + j / 100;
#pragma unroll
        for (int ti = 0; ti < 32; ti++)
            x0p[(size_t)(t0 + ti) * 400 + dst] = (_Float16)(acc[ti] + bb);
    }
}

// ================= Two-CU pipelined scan =================
// grid=2, block=512 (8 waves, 2/SIMD via waves_per_eu(2,2) -> 128 arch VGPRs,
// the empirically proven allocation; 13-wave blocks provably cap at 64+spill).
// Block 0 = layer-0 scan; block 1 = layer-1 scan, consuming the h0 stream via
// global h0seq (agent-scope: per-XCD L2s are not coherent). Block 1 lags; no
// back-pressure needed since h0seq holds the full sequence.
//
// Roles per block: lanes 0..399 = MV+update (thread j: gate g=j&3, unit u=j>>2,
// row r=g*100+u); lanes 448..511 = helper wave (separate wave -> its vmcnt
// waits never stall the MV waves).
//
// Gate nonlinearity: per-lane branchless (lane g==2: tanh = 2*sig(2x)-1), then
// leader (g==0) gathers f/g/o via quad_perm DPP. One lgkm-only barrier per tick.

#define TICK0(T_, XREG_, TNEXT_, P_) do {                                                    \
    if (j < 400) {                                                                           \
        float xc_ = XREG_;                                                                   \
        int tn_ = (TNEXT_) < T_STEPS ? (TNEXT_) : T_STEPS - 1;                               \
        XREG_ = (float)x0p[(size_t)tn_ * 400 + j];                                           \
        const float4* h4_ = (const float4*)hbuf[P_];                                         \
        float aa_ = xc_, ab_ = 0.f, ac_ = 0.f, ad_ = 0.f;                                    \
        _Pragma("unroll")                                                                    \
        for (int c_ = 0; c_ < 12; c_++) {                                                    \
            float4 v_ = h4_[c_];                                                             \
            aa_ = fdot2(w0[4 * c_ + 0], H2BC(v_.x), aa_);                                    \
            ab_ = fdot2(w0[4 * c_ + 1], H2BC(v_.y), ab_);                                    \
            ac_ = fdot2(w0[4 * c_ + 2], H2BC(v_.z), ac_);                                    \
            ad_ = fdot2(w0[4 * c_ + 3], H2BC(v_.w), ad_);                                    \
        }                                                                                    \
        { float2 v_ = *(const float2*)((const char*)hbuf[P_] + 192);                         \
          aa_ = fdot2(w0[48], H2BC(v_.x), aa_);                                              \
          ab_ = fdot2(w0[49], H2BC(v_.y), ab_); }                                            \
        float s0_ = (aa_ + ab_) + (ac_ + ad_);                                               \
        float nl_ = __builtin_fmaf(sigf(s0_ * s_), s_, addc_);                               \
        float fg_ = qperm<0xB1>(nl_), gg_ = qperm<0x4E>(nl_), og_ = qperm<0x1B>(nl_);        \
        if ((j & 3) == 0) {                                                                  \
            int u_ = j >> 2;                                                                 \
            c0 = fg_ * c0 + nl_ * gg_;                                                       \
            float h0v_ = og_ * tanh_f(c0);                                                   \
            hbuf[1 - (P_)][u_] = (_Float16)h0v_;                                             \
            if ((T_) == T_STEPS - 1) { outTail[u_] = h0v_; outTail[200 + u_] = c0; }         \
        }                                                                                    \
    } else if (j >= 448) {                                                                   \
        int k_ = j - 448;                                                                    \
        if (k_ < 50 && (T_) >= 1) {                                                          \
            unsigned v_ = ((const unsigned*)hbuf[P_])[k_];                                   \
            __hip_atomic_store(&h0seq[(size_t)((T_) - 1) * 50 + k_], v_,                     \
                               __ATOMIC_RELAXED, __HIP_MEMORY_SCOPE_AGENT);                  \
        }                                                                                    \
        if (k_ == 0 && ((T_) & 7) == 7)                                                      \
            __hip_atomic_store(flag, (unsigned)(T_),                                         \
                               __ATOMIC_RELEASE, __HIP_MEMORY_SCOPE_AGENT);                  \
    }                                                                                        \
    bar_lds();                                                                               \
} while (0)

// Block-1 tick: MV reads hbuf[P] = {h0(T_) [0..99], h1(T_-1) [104..203]}.
// Helper: ds_write h0(T_+1) (reg WREG_, loaded last tick) into hbuf[1-P];
// poll flag (register-cached; block 0 runs ahead so steady-state polls are
// free) and issue the load of h0(T_+2) into LREG_ (2-tick latency budget).
#define TICK1(T_, P_, WREG_, LREG_) do {                                                     \
    if (j < 400) {                                                                           \
        const char* hb_ = (const char*)hbuf[P_];                                             \
        const float4* u0_ = (const float4*)hb_;                                              \
        const float4* u1_ = (const float4*)(hb_ + 208);                                      \
        float aa_ = b1c, ab_ = 0.f, ac_ = 0.f, ad_ = 0.f;                                    \
        _Pragma("unroll")                                                                    \
        for (int c_ = 0; c_ < 12; c_++) {                                                    \
            float4 v_ = u0_[c_];                                                             \
            aa_ = fdot2(w1[4 * c_ + 0], H2BC(v_.x), aa_);                                    \
            ab_ = fdot2(w1[4 * c_ + 1], H2BC(v_.y), ab_);                                    \
            ac_ = fdot2(w1[4 * c_ + 2], H2BC(v_.z), ac_);                                    \
            ad_ = fdot2(w1[4 * c_ + 3], H2BC(v_.w), ad_);                                    \
        }                                                                                    \
        { float2 v_ = *(const float2*)(hb_ + 192);                                           \
          aa_ = fdot2(w1[48], H2BC(v_.x), aa_);                                              \
          ab_ = fdot2(w1[49], H2BC(v_.y), ab_); }                                            \
        _Pragma("unroll")                                                                    \
        for (int c_ = 0; c_ < 12; c_++) {                                                    \
            float4 v_ = u1_[c_];                                                             \
            aa_ = fdot2(w1[50 + 4 * c_ + 0], H2BC(v_.x), aa_);                               \
            ab_ = fdot2(w1[50 + 4 * c_ + 1], H2BC(v_.y), ab_);                               \
            ac_ = fdot2(w1[50 + 4 * c_ + 2], H2BC(v_.z), ac_);                               \
            ad_ = fdot2(w1[50 + 4 * c_ + 3], H2BC(v_.w), ad_);                               \
        }                                                                                    \
        { float2 v_ = *(const float2*)(hb_ + 400);                                           \
          aa_ = fdot2(w1[98], H2BC(v_.x), aa_);                                              \
          ab_ = fdot2(w1[99], H2BC(v_.y), ab_); }                                            \
        float s1_ = (aa_ + ab_) + (ac_ + ad_);                                               \
        float nl_ = __builtin_fmaf(sigf(s1_ * s_), s_, addc_);                               \
        float fg_ = qperm<0xB1>(nl_), gg_ = qperm<0x4E>(nl_), og_ = qperm<0x1B>(nl_);        \
        if ((j & 3) == 0) {                                                                  \
            int u_ = j >> 2;                                                                 \
            c1 = fg_ * c1 + nl_ * gg_;                                                       \
            float h1v_ = og_ * tanh_f(c1);                                                   \
            hbuf[1 - (P_)][104 + u_] = (_Float16)h1v_;                                       \
            h1s[(size_t)(T_) * 100 + u_] = h1v_;                                             \
            if ((T_) == T_STEPS - 1) { outTail[100 + u_] = h1v_; outTail[300 + u_] = c1; }   \
        }                                                                                    \
    } else if (j >= 448) {                                                                   \
        int k_ = j - 448;                                                                    \
        if (k_ < 50) {                                                                       \
            if ((T_) + 1 < T_STEPS) ((unsigned*)hbuf[1 - (P_)])[k_] = WREG_;                 \
            if ((T_) + 2 < T_STEPS) {                                                        \
                int need_ = (T_) + 3;                                                        \
                if ((int)fcache < need_) {                                                   \
                    unsigned f_;                                                             \
                    while ((int)(f_ = __hip_atomic_load(flag, __ATOMIC_RELAXED,              \
                                                        __HIP_MEMORY_SCOPE_AGENT)) < need_) \
                        __builtin_amdgcn_s_sleep(2);                                         \
                    fcache = f_;                                                             \
                    asm volatile("" ::: "memory");                                           \
                }                                                                            \
                LREG_ = __hip_atomic_load(&h0seq[(size_t)((T_) + 2) * 50 + k_],              \
                                          __ATOMIC_RELAXED, __HIP_MEMORY_SCOPE_AGENT);       \
            }                                                                                \
        }                                                                                    \
    }                                                                                        \
    bar_lds();                                                                               \
} while (0)

__global__ __launch_bounds__(512) __attribute__((amdgpu_waves_per_eu(2, 2)))
void k_scan2(const _Float16* __restrict__ x0p,
             const float* __restrict__ Whh0,
             const float* __restrict__ Wih1,
             const float* __restrict__ Whh1,
             const float* __restrict__ bih1,
             const float* __restrict__ bhh1,
             float* __restrict__ h1s,
             float* __restrict__ outTail,
             unsigned* __restrict__ h0seq,
             unsigned* __restrict__ flag) {
    // double-buffered f16 state. Block0: h0 at [b][0..99]. Block1: h0 at
    // [b][0..99], h1 at [b][104..203] (8B pad keeps float4 reads 16B-aligned).
    __shared__ __align__(16) _Float16 hbuf[2][208];
    const int j = threadIdx.x;
    const int g4 = j & 3;
    // branchless gate NL: lane g==2 computes tanh = 2*sig(2x)-1
    const float s_ = (g4 == 2) ? 2.f : 1.f;
    const float addc_ = (g4 == 2) ? -1.f : 0.f;

    if (blockIdx.x == 0) {
        // ---------------- layer 0 ----------------
        h2 w0[50];
        float xa = 0.f, xb = 0.f, c0 = 0.f;
        if (j < 400) {
            int r = g4 * 100 + (j >> 2);
            const float2* p0 = (const float2*)(Whh0 + r * 100);
#pragma unroll
            for (int k = 0; k < 50; k++) { float2 v = p0[k]; h2 q; q.x = (_Float16)v.x; q.y = (_Float16)v.y; w0[k] = q; }
            xa = (float)x0p[j];          // x(0), permuted layout
            xb = (float)x0p[400 + j];    // x(1)
        }
        if (j < 208) ((unsigned*)hbuf)[j] = 0u;
        __syncthreads();

        for (int t = 0; t < T_STEPS; t += 2) {
            TICK0(t, xa, t + 2, 0);      // read hbuf[0], write hbuf[1]
            TICK0(t + 1, xb, t + 3, 1);  // read hbuf[1], write hbuf[0]
        }
        // final: h0(T-1) sits in hbuf[0]; publish it + final flag
        if (j >= 448) {
            int k = j - 448;
            if (k < 50) {
                unsigned v = ((const unsigned*)hbuf[0])[k];
                __hip_atomic_store(&h0seq[(size_t)(T_STEPS - 1) * 50 + k], v,
                                   __ATOMIC_RELAXED, __HIP_MEMORY_SCOPE_AGENT);
            }
            if (k == 0)
                __hip_atomic_store(flag, (unsigned)T_STEPS,
                                   __ATOMIC_RELEASE, __HIP_MEMORY_SCOPE_AGENT);
        }
    } else {
        // ---------------- layer 1 ----------------
        h2 w1[100];  // [W_ih_l1 row r | W_hh_l1 row r]
        float b1c = 0.f, c1 = 0.f;
        unsigned vA = 0, vB = 0, fcache = 0;
        if (j < 400) {
            int r = g4 * 100 + (j >> 2);
            const float2* p1 = (const float2*)(Wih1 + r * 100);
#pragma unroll
            for (int k = 0; k < 50; k++) { float2 v = p1[k]; h2 q; q.x = (_Float16)v.x; q.y = (_Float16)v.y; w1[k] = q; }
            const float2* p2 = (const float2*)(Whh1 + r * 100);
#pragma unroll
            for (int k = 0; k < 50; k++) { float2 v = p2[k]; h2 q; q.x = (_Float16)v.x; q.y = (_Float16)v.y; w1[50 + k] = q; }
            b1c = bih1[r] + bhh1[r];
        }
        if (j < 208) ((unsigned*)hbuf)[j] = 0u;
        __syncthreads();
        // prologue: helper waits for h0(0),h0(1); stages h0(0) into hbuf[0]
        if (j >= 448) {
            int k = j - 448;
            unsigned f_;
            while ((int)(f_ = __hip_atomic_load(flag, __ATOMIC_RELAXED, __HIP_MEMORY_SCOPE_AGENT)) < 2)
                __builtin_amdgcn_s_sleep(8);
            fcache = f_;
            asm volatile("" ::: "memory");
            if (k < 50) {
                vA = __hip_atomic_load(&h0seq[k], __ATOMIC_RELAXED, __HIP_MEMORY_SCOPE_AGENT);
                vB = __hip_atomic_load(&h0seq[50 + k], __ATOMIC_RELAXED, __HIP_MEMORY_SCOPE_AGENT);
                ((unsigned*)hbuf[0])[k] = vA;  // h0(0)
            }
        }
        __syncthreads();

        for (int t = 0; t < T_STEPS; t += 2) {
            TICK1(t, 0, vB, vA);      // read hbuf[0]; stage h0(t+1)=vB; load vA=h0(t+2)
            TICK1(t + 1, 1, vA, vB);  // read hbuf[1]; stage h0(t+2)=vA; load vB=h0(t+3)
        }
    }
}

// ---------------- C: outputs[t][d] = h1s[t] . W_out[d] + b_out[d] ----------------
__global__ __launch_bounds__(320) void k_out(const float* __restrict__ h1s,
                                             const float* __restrict__ Wout,
                                             const float* __restrict__ bout,
                                             float* __restrict__ out) {
    __shared__ float hs[32 * 100];
    int t0 = blockIdx.x * 32;
    for (int idx = threadIdx.x; idx < 3200; idx += 320) hs[idx] = h1s[(size_t)t0 * 100 + idx];
    __syncthreads();
    int d = threadIdx.x;
    if (d < 300) {
        float acc[32];
#pragma unroll
        for (int i = 0; i < 32; i++) acc[i] = 0.f;
        const float4* w4 = (const float4*)(Wout + d * 100);
        const float4* h4 = (const float4*)hs;
        for (int j4 = 0; j4 < 25; j4++) {
            float4 w = w4[j4];
#pragma unroll
            for (int ti = 0; ti < 32; ti++) {
                float4 h = h4[ti * 25 + j4];
                acc[ti] += w.x * h.x + w.y * h.y + w.z * h.z + w.w * h.w;
            }
        }
        float bb = bout[d];
#pragma unroll
        for (int ti = 0; ti < 32; ti++) out[(size_t)(t0 + ti) * 300 + d] = acc[ti] + bb;
    }
}

extern "C" void kernel_launch(void* const* d_in, const int* in_sizes, int n_in,
                              void* d_out, int out_size, void* d_ws, size_t ws_size,
                              hipStream_t stream) {
    const float* inputs = (const float*)d_in[0];
    const float* W_inp  = (const float*)d_in[1];
    const float* b_inp  = (const float*)d_in[2];
    const float* W_ih0  = (const float*)d_in[3];
    const float* W_hh0  = (const float*)d_in[4];
    const float* b_ih0  = (const float*)d_in[5];
    const float* b_hh0  = (const float*)d_in[6];
    const float* W_ih1  = (const float*)d_in[7];
    const float* W_hh1  = (const float*)d_in[8];
    const float* b_ih1  = (const float*)d_in[9];
    const float* b_hh1  = (const float*)d_in[10];
    const float* W_out  = (const float*)d_in[11];
    const float* b_out  = (const float*)d_in[12];
    float* out = (float*)d_out;

    char* ws = (char*)d_ws;
    _Float16* x0p = (_Float16*)ws;                         // 32768*400*2 = 26,214,400 B
    float* h1s = (float*)(ws + 26214400);                  // 32768*100*4 = 13,107,200 B
    float* Wc  = (float*)(ws + 26214400 + 13107200);       // 400*300*4   =    480,000 B
    float* bc  = Wc + 120000;                              // 400*4 B

    // h0 stream + flag live in the out buffer's scratch region (fully
    // overwritten by k_out afterwards): h0seq = 32768*50 u32 = 6,553,600 B,
    // flag at u32 index 1,638,400 -- both far below OUT_BASE*4 = 39,321,600 B.
    unsigned* h0seq = (unsigned*)out;
    unsigned* flagp = (unsigned*)out + 1638400;
    float* outTail = out + OUT_BASE;

    hipMemsetAsync(flagp, 0, 4, stream);
    k_precomp<<<471, 256, 0, stream>>>(W_inp, b_inp, W_ih0, b_ih0, b_hh0, Wc, bc);
    k_xproj<<<1024, 512, 0, stream>>>(inputs, Wc, bc, x0p);

    void* args[] = {(void*)&x0p, (void*)&W_hh0, (void*)&W_ih1, (void*)&W_hh1,
                    (void*)&b_ih1, (void*)&b_hh1, (void*)&h1s, (void*)&outTail,
                    (void*)&h0seq, (void*)&flagp};
    hipLaunchCooperativeKernel((void*)k_scan2, dim3(2), dim3(512), args, 0, stream);

    k_out<<<1024, 320, 0, stream>>>(h1s, W_out, b_out, out);
}

// Round 8
// 23908.392 us; speedup vs baseline: 2.1348x; 1.0634x over previous
//
#include <hip/hip_runtime.h>

#define T_STEPS 32768
#define OUT_BASE 9830400  // 32768*300

typedef _Float16 h2 __attribute__((ext_vector_type(2)));
#define H2BC(f_) __builtin_bit_cast(h2, f_)

// relaxed/release agent-scope atomics (round-5-proven cross-XCD protocol)
#define ALD(p)     __hip_atomic_load((p), __ATOMIC_RELAXED, __HIP_MEMORY_SCOPE_AGENT)
#define AST(p, v)  __hip_atomic_store((p), (v), __ATOMIC_RELAXED, __HIP_MEMORY_SCOPE_AGENT)
#define ASTR(p, v) __hip_atomic_store((p), (v), __ATOMIC_RELEASE, __HIP_MEMORY_SCOPE_AGENT)
#define CFENCE()   asm volatile("" ::: "memory")

__device__ __forceinline__ float fdot2(h2 a, h2 b, float c) {
#if __has_builtin(__builtin_amdgcn_fdot2)
    return __builtin_amdgcn_fdot2(a, b, c, false);
#else
    return c + (float)a.x * (float)b.x + (float)a.y * (float)b.y;
#endif
}

__device__ __forceinline__ float sigf(float x) { return 1.f / (1.f + __expf(-x)); }

__device__ __forceinline__ float tanh_f(float x) {
    float a = fabsf(x);
    float e = __expf(-2.f * a);
    float t = (1.f - e) / (1.f + e);
    return x < 0.f ? -t : t;
}

// quad_perm DPP cross-lane read. CTRL: 0xB1=xor1, 0x4E=xor2, 0x1B=xor3.
template <int CTRL>
__device__ __forceinline__ float qperm(float x) {
#if __has_builtin(__builtin_amdgcn_update_dpp)
    return __builtin_bit_cast(
        float, __builtin_amdgcn_update_dpp(0, __builtin_bit_cast(int, x), CTRL, 0xF, 0xF, true));
#else
    return __shfl_xor(x, CTRL == 0xB1 ? 1 : (CTRL == 0x4E ? 2 : 3));
#endif
}

// LDS-only barrier: keep global loads/stores (vmcnt) in flight across ticks.
__device__ __forceinline__ void bar_lds() {
    asm volatile("s_waitcnt lgkmcnt(0)\n\ts_barrier" ::: "memory");
}

// load 25 f16-pairs of one row-half (50 consecutive floats) into h2 regs
__device__ __forceinline__ void ldw(h2* w, const float* p) {
#pragma unroll
    for (int k = 0; k < 25; k++) {
        float2 v = ((const float2*)p)[k];
        h2 t; t.x = (_Float16)v.x; t.y = (_Float16)v.y; w[k] = t;
    }
}

// half-row MV: 25 h2 from rec (6 x b128 + 1 x b32, all 16B-aligned) x two rows
__device__ __forceinline__ float2 mv25(const h2* wA, const h2* wB, const char* rec) {
    const float4* hv = (const float4*)rec;
    float pA = 0.f, pB = 0.f;
#pragma unroll
    for (int c = 0; c < 6; c++) {
        float4 v = hv[c];
        pA = fdot2(wA[4 * c + 0], H2BC(v.x), pA); pB = fdot2(wB[4 * c + 0], H2BC(v.x), pB);
        pA = fdot2(wA[4 * c + 1], H2BC(v.y), pA); pB = fdot2(wB[4 * c + 1], H2BC(v.y), pB);
        pA = fdot2(wA[4 * c + 2], H2BC(v.z), pA); pB = fdot2(wB[4 * c + 2], H2BC(v.z), pB);
        pA = fdot2(wA[4 * c + 3], H2BC(v.w), pA); pB = fdot2(wB[4 * c + 3], H2BC(v.w), pB);
    }
    float vl = *(const float*)(rec + 96);
    pA = fdot2(wA[24], H2BC(vl), pA); pB = fdot2(wB[24], H2BC(vl), pB);
    return make_float2(pA, pB);
}

// ---------------- A0: Wc = W_ih_l0 @ W_inp  [400x300]; bc = W_ih_l0@b_inp + b_ih0 + b_hh0 ----------------
__global__ void k_precomp(const float* __restrict__ W_inp, const float* __restrict__ b_inp,
                          const float* __restrict__ W_ih0, const float* __restrict__ b_ih0,
                          const float* __restrict__ b_hh0,
                          float* __restrict__ Wc, float* __restrict__ bc) {
    int idx = blockIdx.x * 256 + threadIdx.x;
    if (idx < 120000) {
        int r = idx / 300, d = idx % 300;
        float acc = 0.f;
        for (int h = 0; h < 100; h++) acc += W_ih0[r * 100 + h] * W_inp[h * 300 + d];
        Wc[idx] = acc;
    } else if (idx < 120400) {
        int r = idx - 120000;
        float acc = b_ih0[r] + b_hh0[r];
        for (int h = 0; h < 100; h++) acc += W_ih0[r * 100 + h] * b_inp[h];
        bc[r] = acc;
    }
}

// ---------------- A1: x0p[t][u*4+g] = inputs[t] . Wc[g*100+u] + bc, stored f16 ----------------
__global__ __launch_bounds__(512) void k_xproj(const float* __restrict__ inp,
                                               const float* __restrict__ Wc,
                                               const float* __restrict__ bc,
                                               _Float16* __restrict__ x0p) {
    __shared__ float xs[32 * 300];
    int t0 = blockIdx.x * 32;
    for (int idx = threadIdx.x; idx < 9600; idx += 512) xs[idx] = inp[(size_t)t0 * 300 + idx];
    __syncthreads();
    int j = threadIdx.x;
    if (j < 400) {
        float acc[32];
#pragma unroll
        for (int i = 0; i < 32; i++) acc[i] = 0.f;
        const float4* w4 = (const float4*)(Wc + j * 300);
        const float4* x4 = (const float4*)xs;
        for (int d4 = 0; d4 < 75; d4++) {
            float4 w = w4[d4];
#pragma unroll
            for (int ti = 0; ti < 32; ti++) {
                float4 x = x4[ti * 75 + d4];
                acc[ti] += w.x * x.x + w.y * x.y + w.z * x.z + w.w * x.w;
            }
        }
        float bb = bc[j];
        int dst = (j % 100) * 4 + j / 100;
#pragma unroll
        for (int ti = 0; ti < 32; ti++)
            x0p[(size_t)(t0 + ti) * 400 + dst] = (_Float16)(acc[ti] + bb);
    }
}

// ================= Two-CU pipelined scan (round-5 structure) + half-split MV =================
// grid=2 cooperative, 512 thr (8 waves, waves_per_eu(2,2) -> proven 128-reg alloc).
// B0 = layer-0 scan, B1 = layer-1 scan consuming the h0 stream via global h0seq
// (agent-scope; per-XCD L2s not coherent). Protocol, launch shape, scratch layout
// IDENTICAL to the round-5 pass. Only change: half-split MV.
//
// Half-split MV: lane j<400: q=j&3, u=j>>2, H=q&1, gA=2*(q>>1). Lane holds halves
// (cols 50H..50H+49) of gate rows {gA, gA+1}. After mv25, p += dpp_xor1(p)
// completes both rows; (H ? rowB : rowA) leaves lane q holding its OWN gate row q.
// Cuts LDS reads/lane/tick: B0 13 -> 7, B1 26 -> 14 (the round-5 limiter).
//
// LDS record = 56 u32: half0 f16[0..49] @byte0, half1 f16[50..99] @byte112
// (both halves 16B-aligned; pads at u32 25-27, 53-55 never read).
// lds[P][0..55] = h0 record, lds[P][56..111] = h1 record (B1 only).

#define B0TICK(T_, XR_, P_) do {                                                             \
    if (j < 400) {                                                                           \
        float xc_ = XR_;                                                                     \
        int tn_ = (T_) + 2 < T_STEPS ? (T_) + 2 : T_STEPS - 1;                               \
        XR_ = (float)x0p[(size_t)tn_ * 400 + j];                                             \
        float2 p_ = mv25(wA, wB, (const char*)lds[P_] + hoff);                               \
        float pA_ = p_.x + qperm<0xB1>(p_.x);                                                \
        float pB_ = p_.y + qperm<0xB1>(p_.y);                                                \
        float sv_ = (H ? pB_ : pA_) + xc_;                                                   \
        float nl_ = __builtin_fmaf(sigf(sv_ * s_), s_, addc_);                               \
        float fg_ = qperm<0xB1>(nl_), gg_ = qperm<0x4E>(nl_), og_ = qperm<0x1B>(nl_);        \
        if (q == 0) {                                                                        \
            c0 = fg_ * c0 + nl_ * gg_;                                                       \
            float h0v_ = og_ * tanh_f(c0);                                                   \
            ((_Float16*)lds[1 - (P_)])[hidx] = (_Float16)h0v_;                               \
            if ((T_) == T_STEPS - 1) { outTail[u] = h0v_; outTail[200 + u] = c0; }           \
        }                                                                                    \
    } else if (j >= 448) {                                                                   \
        if (kk < 50 && (T_) >= 1)                                                            \
            AST(&h0seq[(size_t)((T_) - 1) * 50 + kk], lds[P_][pidx]);                        \
        if (kk == 0 && (((T_) & 7) == 7)) ASTR(&flags[0], (unsigned)(T_));                   \
    }                                                                                        \
    bar_lds();                                                                               \
} while (0)

// B1 tick: MV reads lds[P] = {h0(T) record, h1(T-1) record}. Helper (lanes
// 448+, own wave -> own vmcnt domain): stage h0(T+1) (reg WREG_, loaded last
// tick) into lds[1-P]; poll flag (register-cached; B0 runs ahead so steady-
// state polls are free) and issue the load of h0(T+2) into LREG_.
#define B1TICK(T_, P_, WREG_, LREG_) do {                                                    \
    if (j < 400) {                                                                           \
        const char* hb_ = (const char*)lds[P_];                                              \
        float2 p0_ = mv25(wA0, wB0, hb_ + hoff);        /* W_ih1 . h0(T) */                  \
        float2 p1_ = mv25(wA1, wB1, hb_ + 224 + hoff);  /* W_hh1 . h1(T-1) */                \
        float pA_ = p0_.x + p1_.x;  pA_ += qperm<0xB1>(pA_);                                 \
        float pB_ = p0_.y + p1_.y;  pB_ += qperm<0xB1>(pB_);                                 \
        float sv_ = (H ? pB_ : pA_) + bz;                                                    \
        float nl_ = __builtin_fmaf(sigf(sv_ * s_), s_, addc_);                               \
        float fg_ = qperm<0xB1>(nl_), gg_ = qperm<0x4E>(nl_), og_ = qperm<0x1B>(nl_);        \
        if (q == 0) {                                                                        \
            c1 = fg_ * c1 + nl_ * gg_;                                                       \
            float h1v_ = og_ * tanh_f(c1);                                                   \
            ((_Float16*)(lds[1 - (P_)] + 56))[hidx] = (_Float16)h1v_;                        \
            h1s[(size_t)(T_) * 100 + u] = h1v_;                                              \
            if ((T_) == T_STEPS - 1) { outTail[100 + u] = h1v_; outTail[300 + u] = c1; }     \
        }                                                                                    \
    } else if (j >= 448) {                                                                   \
        if (kk < 50) {                                                                       \
            if ((T_) + 1 < T_STEPS) lds[1 - (P_)][pidx] = WREG_;                             \
            if ((T_) + 2 < T_STEPS) {                                                        \
                unsigned need_ = (unsigned)(T_) + 3u;                                        \
                if (fcache < need_) {                                                        \
                    unsigned f_;                                                             \
                    while ((f_ = ALD(flags)) < need_) __builtin_amdgcn_s_sleep(2);           \
                    fcache = f_;                                                             \
                    CFENCE();                                                                \
                }                                                                            \
                LREG_ = ALD(&h0seq[(size_t)((T_) + 2) * 50 + kk]);                           \
            }                                                                                \
        }                                                                                    \
    }                                                                                        \
    bar_lds();                                                                               \
} while (0)

__global__ __launch_bounds__(512) __attribute__((amdgpu_waves_per_eu(2, 2)))
void k_scan2(const _Float16* __restrict__ x0p,
             const float* __restrict__ Whh0,
             const float* __restrict__ Wih1,
             const float* __restrict__ Whh1,
             const float* __restrict__ bih1,
             const float* __restrict__ bhh1,
             float* __restrict__ h1s,
             float* __restrict__ outTail,
             unsigned* __restrict__ h0seq,
             unsigned* __restrict__ flags) {
    __shared__ __align__(16) unsigned lds[2][112];  // [P]{h0 rec | h1 rec}
    const int j = threadIdx.x;
    const int q = j & 3, u = j >> 2, H = q & 1, gA = (q >> 1) * 2;
    const int hoff = H * 112;                       // byte offset of my half in a record
    const int hidx = (u < 50) ? u : 56 + (u - 50);  // f16 index of h[u] in padded record
    const int kk = j - 448;
    const int pidx = (kk < 25) ? kk : kk + 3;       // u32 index of packed pair kk
    const float s_ = (q == 2) ? 2.f : 1.f;          // lane q==2: tanh = 2*sig(2x)-1
    const float addc_ = (q == 2) ? -1.f : 0.f;

    if (blockIdx.x == 0) {
        // ---------------- B0: layer-0 scan ----------------
        h2 wA[25], wB[25];
        float xa = 0.f, xb = 0.f, c0 = 0.f;
        if (j < 400) {
            int r0 = gA * 100 + u;
            ldw(wA, Whh0 + r0 * 100 + 50 * H);
            ldw(wB, Whh0 + (r0 + 100) * 100 + 50 * H);
            xa = (float)x0p[j];          // x(0), permuted layout
            xb = (float)x0p[400 + j];    // x(1)
        }
        if (j < 224) ((unsigned*)lds)[j] = 0u;  // h0(-1)=0, both buffers
        __syncthreads();

        for (int t = 0; t < T_STEPS; t += 2) {
            B0TICK(t, xa, 0);      // read lds[0], write lds[1]
            B0TICK(t + 1, xb, 1);  // read lds[1], write lds[0]
        }
        if (j >= 448) {  // publish h0(T-1) (sits in lds[0]) + final flag
            if (kk < 50) AST(&h0seq[(size_t)(T_STEPS - 1) * 50 + kk], lds[0][pidx]);
            if (kk == 0) ASTR(&flags[0], (unsigned)T_STEPS);
        }
    } else {
        // ---------------- B1: layer-1 scan ----------------
        h2 wA0[25], wB0[25], wA1[25], wB1[25];
        float bz = 0.f, c1 = 0.f;
        unsigned vA = 0, vB = 0, fcache = 0;
        if (j < 400) {
            int r0 = gA * 100 + u;
            ldw(wA0, Wih1 + r0 * 100 + 50 * H);
            ldw(wB0, Wih1 + (r0 + 100) * 100 + 50 * H);
            ldw(wA1, Whh1 + r0 * 100 + 50 * H);
            ldw(wB1, Whh1 + (r0 + 100) * 100 + 50 * H);
            int ro = q * 100 + u;  // my OWN gate row (post-select)
            bz = bih1[ro] + bhh1[ro];
        }
        if (j < 224) ((unsigned*)lds)[j] = 0u;  // h1(-1)=0 (+ h0 recs cleared)
        __syncthreads();
        // prologue: helper waits for h0(0),h0(1); stages h0(0) into lds[0]
        if (j >= 448) {
            unsigned f_;
            while ((f_ = ALD(flags)) < 2u) __builtin_amdgcn_s_sleep(8);
            fcache = f_;
            CFENCE();
            if (kk < 50) {
                vA = ALD(&h0seq[kk]);        // h0(0) pair kk
                vB = ALD(&h0seq[50 + kk]);   // h0(1)
                lds[0][pidx] = vA;
            }
        }
        __syncthreads();

        for (int t = 0; t < T_STEPS; t += 2) {
            B1TICK(t, 0, vB, vA);      // read lds[0]; stage h0(t+1)=vB; load vA=h0(t+2)
            B1TICK(t + 1, 1, vA, vB);  // read lds[1]; stage h0(t+2)=vA; load vB=h0(t+3)
        }
    }
}

// ---------------- C: outputs[t][d] = h1s[t] . W_out[d] + b_out[d] ----------------
__global__ __launch_bounds__(320) void k_out(const float* __restrict__ h1s,
                                             const float* __restrict__ Wout,
                                             const float* __restrict__ bout,
                                             float* __restrict__ out) {
    __shared__ float hs[32 * 100];
    int t0 = blockIdx.x * 32;
    for (int idx = threadIdx.x; idx < 3200; idx += 320) hs[idx] = h1s[(size_t)t0 * 100 + idx];
    __syncthreads();
    int d = threadIdx.x;
    if (d < 300) {
        float acc[32];
#pragma unroll
        for (int i = 0; i < 32; i++) acc[i] = 0.f;
        const float4* w4 = (const float4*)(Wout + d * 100);
        const float4* h4 = (const float4*)hs;
        for (int j4 = 0; j4 < 25; j4++) {
            float4 w = w4[j4];
#pragma unroll
            for (int ti = 0; ti < 32; ti++) {
                float4 h = h4[ti * 25 + j4];
                acc[ti] += w.x * h.x + w.y * h.y + w.z * h.z + w.w * h.w;
            }
        }
        float bb = bout[d];
#pragma unroll
        for (int ti = 0; ti < 32; ti++) out[(size_t)(t0 + ti) * 300 + d] = acc[ti] + bb;
    }
}

extern "C" void kernel_launch(void* const* d_in, const int* in_sizes, int n_in,
                              void* d_out, int out_size, void* d_ws, size_t ws_size,
                              hipStream_t stream) {
    const float* inputs = (const float*)d_in[0];
    const float* W_inp  = (const float*)d_in[1];
    const float* b_inp  = (const float*)d_in[2];
    const float* W_ih0  = (const float*)d_in[3];
    const float* W_hh0  = (const float*)d_in[4];
    const float* b_ih0  = (const float*)d_in[5];
    const float* b_hh0  = (const float*)d_in[6];
    const float* W_ih1  = (const float*)d_in[7];
    const float* W_hh1  = (const float*)d_in[8];
    const float* b_ih1  = (const float*)d_in[9];
    const float* b_hh1  = (const float*)d_in[10];
    const float* W_out  = (const float*)d_in[11];
    const float* b_out  = (const float*)d_in[12];
    float* out = (float*)d_out;

    char* ws = (char*)d_ws;
    _Float16* x0p = (_Float16*)ws;                    // 32768*400*2 = 26,214,400 B
    float* h1s = (float*)(ws + 26214400);             // 32768*100*4 = 13,107,200 B
    float* Wc  = (float*)(ws + 26214400 + 13107200);  // 400*300*4   =    480,000 B
    float* bc  = Wc + 120000;                         // 400*4 B

    // h0 stream + flag in the out buffer's scratch region (round-5-proven;
    // fully overwritten by k_out afterwards): h0seq = 32768*50 u32 = 6,553,600 B,
    // flag at u32 index 1,638,400 -- both far below OUT_BASE*4 = 39,321,600 B.
    unsigned* h0seq = (unsigned*)out;
    unsigned* flagp = (unsigned*)out + 1638400;
    float* outTail = out + OUT_BASE;

    hipMemsetAsync(flagp, 0, 4, stream);
    k_precomp<<<471, 256, 0, stream>>>(W_inp, b_inp, W_ih0, b_ih0, b_hh0, Wc, bc);
    k_xproj<<<1024, 512, 0, stream>>>(inputs, Wc, bc, x0p);

    void* args[] = {(void*)&x0p, (void*)&W_hh0, (void*)&W_ih1, (void*)&W_hh1,
                    (void*)&b_ih1, (void*)&b_hh1, (void*)&h1s, (void*)&outTail,
                    (void*)&h0seq, (void*)&flagp};
    hipLaunchCooperativeKernel((void*)k_scan2, dim3(2), dim3(512), args, 0, stream);

    k_out<<<1024, 320, 0, stream>>>(h1s, W_out, b_out, out);
}

// Round 9
// 20725.726 us; speedup vs baseline: 2.4626x; 1.1536x over previous
//
#include <hip/hip_runtime.h>

#define T_STEPS 32768
#define OUT_BASE 9830400  // 32768*300
#define RMASK 16383       // z1 ring = 16384 ticks (26.2 MB, in out-scratch)

typedef _Float16 h2 __attribute__((ext_vector_type(2)));
#define H2BC(f_) __builtin_bit_cast(h2, f_)

// relaxed/release agent-scope atomics (round-5/8-proven cross-XCD protocol)
#define ALD(p)     __hip_atomic_load((p), __ATOMIC_RELAXED, __HIP_MEMORY_SCOPE_AGENT)
#define AST(p, v)  __hip_atomic_store((p), (v), __ATOMIC_RELAXED, __HIP_MEMORY_SCOPE_AGENT)
#define ASTR(p, v) __hip_atomic_store((p), (v), __ATOMIC_RELEASE, __HIP_MEMORY_SCOPE_AGENT)
#define CFENCE()   asm volatile("" ::: "memory")

__device__ __forceinline__ float fdot2(h2 a, h2 b, float c) {
#if __has_builtin(__builtin_amdgcn_fdot2)
    return __builtin_amdgcn_fdot2(a, b, c, false);
#else
    return c + (float)a.x * (float)b.x + (float)a.y * (float)b.y;
#endif
}

__device__ __forceinline__ float sigf(float x) { return 1.f / (1.f + __expf(-x)); }

__device__ __forceinline__ float tanh_f(float x) {
    float a = fabsf(x);
    float e = __expf(-2.f * a);
    float t = (1.f - e) / (1.f + e);
    return x < 0.f ? -t : t;
}

// quad_perm DPP cross-lane read. CTRL: 0xB1=xor1, 0x4E=xor2, 0x1B=xor3.
template <int CTRL>
__device__ __forceinline__ float qperm(float x) {
#if __has_builtin(__builtin_amdgcn_update_dpp)
    return __builtin_bit_cast(
        float, __builtin_amdgcn_update_dpp(0, __builtin_bit_cast(int, x), CTRL, 0xF, 0xF, true));
#else
    return __shfl_xor(x, CTRL == 0xB1 ? 1 : (CTRL == 0x4E ? 2 : 3));
#endif
}

// LDS-only barrier: keep global loads/stores (vmcnt) in flight across ticks.
__device__ __forceinline__ void bar_lds() {
    asm volatile("s_waitcnt lgkmcnt(0)\n\ts_barrier" ::: "memory");
}

// load 25 f16-pairs of one row-half (50 consecutive floats) into h2 regs
__device__ __forceinline__ void ldw(h2* w, const float* p) {
#pragma unroll
    for (int k = 0; k < 25; k++) {
        float2 v = ((const float2*)p)[k];
        h2 t; t.x = (_Float16)v.x; t.y = (_Float16)v.y; w[k] = t;
    }
}

// half-row MV: 25 h2 from rec (6 x b128 + 1 x b32, all 16B-aligned) x two rows
__device__ __forceinline__ float2 mv25(const h2* wA, const h2* wB, const char* rec) {
    const float4* hv = (const float4*)rec;
    float pA = 0.f, pB = 0.f;
#pragma unroll
    for (int c = 0; c < 6; c++) {
        float4 v = hv[c];
        pA = fdot2(wA[4 * c + 0], H2BC(v.x), pA); pB = fdot2(wB[4 * c + 0], H2BC(v.x), pB);
        pA = fdot2(wA[4 * c + 1], H2BC(v.y), pA); pB = fdot2(wB[4 * c + 1], H2BC(v.y), pB);
        pA = fdot2(wA[4 * c + 2], H2BC(v.z), pA); pB = fdot2(wB[4 * c + 2], H2BC(v.z), pB);
        pA = fdot2(wA[4 * c + 3], H2BC(v.w), pA); pB = fdot2(wB[4 * c + 3], H2BC(v.w), pB);
    }
    float vl = *(const float*)(rec + 96);
    pA = fdot2(wA[24], H2BC(vl), pA); pB = fdot2(wB[24], H2BC(vl), pB);
    return make_float2(pA, pB);
}

// ---------------- A0: Wc = W_ih_l0 @ W_inp  [400x300]; bc = W_ih_l0@b_inp + b_ih0 + b_hh0 ----------------
__global__ void k_precomp(const float* __restrict__ W_inp, const float* __restrict__ b_inp,
                          const float* __restrict__ W_ih0, const float* __restrict__ b_ih0,
                          const float* __restrict__ b_hh0,
                          float* __restrict__ Wc, float* __restrict__ bc) {
    int idx = blockIdx.x * 256 + threadIdx.x;
    if (idx < 120000) {
        int r = idx / 300, d = idx % 300;
        float acc = 0.f;
        for (int h = 0; h < 100; h++) acc += W_ih0[r * 100 + h] * W_inp[h * 300 + d];
        Wc[idx] = acc;
    } else if (idx < 120400) {
        int r = idx - 120000;
        float acc = b_ih0[r] + b_hh0[r];
        for (int h = 0; h < 100; h++) acc += W_ih0[r * 100 + h] * b_inp[h];
        bc[r] = acc;
    }
}

// ---------------- A1: x0p[t][u*4+g] = inputs[t] . Wc[g*100+u] + bc, stored f16 ----------------
__global__ __launch_bounds__(512) void k_xproj(const float* __restrict__ inp,
                                               const float* __restrict__ Wc,
                                               const float* __restrict__ bc,
                                               _Float16* __restrict__ x0p) {
    __shared__ float xs[32 * 300];
    int t0 = blockIdx.x * 32;
    for (int idx = threadIdx.x; idx < 9600; idx += 512) xs[idx] = inp[(size_t)t0 * 300 + idx];
    __syncthreads();
    int j = threadIdx.x;
    if (j < 400) {
        float acc[32];
#pragma unroll
        for (int i = 0; i < 32; i++) acc[i] = 0.f;
        const float4* w4 = (const float4*)(Wc + j * 300);
        const float4* x4 = (const float4*)xs;
        for (int d4 = 0; d4 < 75; d4++) {
            float4 w = w4[d4];
#pragma unroll
            for (int ti = 0; ti < 32; ti++) {
                float4 x = x4[ti * 75 + d4];
                acc[ti] += w.x * x.x + w.y * x.y + w.z * x.z + w.w * x.w;
            }
        }
        float bb = bc[j];
        int dst = (j % 100) * 4 + j / 100;
#pragma unroll
        for (int ti = 0; ti < 32; ti++)
            x0p[(size_t)(t0 + ti) * 400 + dst] = (_Float16)(acc[ti] + bb);
    }
}

// ================= Three-CU pipelined scan =================
// grid=3 cooperative, 512 thr (8 waves, waves_per_eu(2,2) -> proven 128-reg alloc).
//   B0: layer-0 scan (round-8 verbatim). Publishes h0 stream (h0seq) + flags[0].
//   Bz: z1(t) = W_ih_l1.h0(t) + b1 streaming GEMM, 16-tick tiles -> z1ring,
//       publishes flags[1] = tiles done. WITH ring backpressure on flags[2]
//       (round 7's corruption bug: Bz is ~3x faster than the scan and laps the
//       16384-tick ring without it).
//   B2: layer-1 scan: gates1 = z1(t) + W_hh_l1.h1(t-1). 50 fdot2/lane (was 100:
//       fdot2 is half-rate, the round-8 limiter); z1 via distance-2 register
//       prefetch from z1ring; publishes progress flags[2] every 256 ticks.
// Wait graph: B0 -> Bz -> B2, back-edge Bz<-B2 only binds when Bz is >16k ticks
// ahead, at which point B2 needs only tiles Bz already produced -> deadlock-free.
// Half-split MV and LDS record layout are round-8 verbatim (lane q&3=q, u=j>>2,
// H=q&1 holds halves of gate rows {gA,gA+1}; record = 56 u32, halves at byte
// 0/112, both 16B-aligned; after xor1-reduce + H-select lane holds row q*100+u).

#define B0TICK(T_, XR_, P_) do {                                                             \
    if (j < 400) {                                                                           \
        float xc_ = XR_;                                                                     \
        int tn_ = (T_) + 2 < T_STEPS ? (T_) + 2 : T_STEPS - 1;                               \
        XR_ = (float)x0p[(size_t)tn_ * 400 + j];                                             \
        float2 p_ = mv25(wA, wB, (const char*)(lds + (P_) * 112) + hoff);                    \
        float pA_ = p_.x + qperm<0xB1>(p_.x);                                                \
        float pB_ = p_.y + qperm<0xB1>(p_.y);                                                \
        float sv_ = (H ? pB_ : pA_) + xc_;                                                   \
        float nl_ = __builtin_fmaf(sigf(sv_ * s_), s_, addc_);                               \
        float fg_ = qperm<0xB1>(nl_), gg_ = qperm<0x4E>(nl_), og_ = qperm<0x1B>(nl_);        \
        if (q == 0) {                                                                        \
            c0 = fg_ * c0 + nl_ * gg_;                                                       \
            float h0v_ = og_ * tanh_f(c0);                                                   \
            ((_Float16*)(lds + (1 - (P_)) * 112))[hidx] = (_Float16)h0v_;                    \
            if ((T_) == T_STEPS - 1) { outTail[u] = h0v_; outTail[200 + u] = c0; }           \
        }                                                                                    \
    } else if (j >= 448) {                                                                   \
        if (kk < 50 && (T_) >= 1)                                                            \
            AST(&h0seq[(size_t)((T_) - 1) * 50 + kk], (lds + (P_) * 112)[pidx]);             \
        if (kk == 0 && (((T_) & 7) == 7)) ASTR(&flags[0], (unsigned)(T_));                   \
    }                                                                                        \
    bar_lds();                                                                               \
} while (0)

// B2 tick: MV reads lds[P] = h1(T-1) record only; z1(T) sits in register ZR_
// (prefetched 2 ticks ago); prefetch z1(T+2). Helper lane 448: verify tile for
// tick T+3 is published (so next tick's prefetch is safe) + progress beacon.
#define B2TICK(T_, ZR_, P_) do {                                                             \
    if (j < 400) {                                                                           \
        float zc_ = ZR_;                                                                     \
        int tn_ = (T_) + 2 < T_STEPS ? (T_) + 2 : T_STEPS - 1;                               \
        ZR_ = ALD(&z1ring[(size_t)(tn_ & RMASK) * 400 + j]);                                 \
        float2 p_ = mv25(wA, wB, (const char*)(lds + (P_) * 112) + hoff);                    \
        float pA_ = p_.x + qperm<0xB1>(p_.x);                                                \
        float pB_ = p_.y + qperm<0xB1>(p_.y);                                                \
        float sv_ = (H ? pB_ : pA_) + zc_; /* z1 already includes b_ih1+b_hh1 */             \
        float nl_ = __builtin_fmaf(sigf(sv_ * s_), s_, addc_);                               \
        float fg_ = qperm<0xB1>(nl_), gg_ = qperm<0x4E>(nl_), og_ = qperm<0x1B>(nl_);        \
        if (q == 0) {                                                                        \
            c1 = fg_ * c1 + nl_ * gg_;                                                       \
            float h1v_ = og_ * tanh_f(c1);                                                   \
            ((_Float16*)(lds + (1 - (P_)) * 112))[hidx] = (_Float16)h1v_;                    \
            h1s[(size_t)(T_) * 100 + u] = h1v_;                                              \
            if ((T_) == T_STEPS - 1) { outTail[100 + u] = h1v_; outTail[300 + u] = c1; }     \
        }                                                                                    \
    } else if (j == 448) {                                                                   \
        int tq_ = (T_) + 3 < T_STEPS ? (T_) + 3 : T_STEPS - 1;                               \
        unsigned need_ = (unsigned)(tq_ >> 4) + 1u;                                          \
        if (zdc < need_) {                                                                   \
            while ((zdc = ALD(&flags[1])) < need_) __builtin_amdgcn_s_sleep(2);              \
            CFENCE();                                                                        \
        }                                                                                    \
        if (((T_) & 255) == 255) ASTR(&flags[2], (unsigned)(T_) + 1u);                       \
    }                                                                                        \
    bar_lds();                                                                               \
} while (0)

__global__ __launch_bounds__(512) __attribute__((amdgpu_waves_per_eu(2, 2)))
void k_scan3(const _Float16* __restrict__ x0p,
             const float* __restrict__ Whh0,
             const float* __restrict__ Wih1,
             const float* __restrict__ Whh1,
             const float* __restrict__ bih1,
             const float* __restrict__ bhh1,
             float* __restrict__ h1s,
             float* __restrict__ outTail,
             unsigned* __restrict__ h0seq,
             float* __restrict__ z1ring,
             unsigned* __restrict__ flags) {
    // B0/B2: double-buffered record at lds[P*112 .. P*112+55]. Bz: 16 records.
    __shared__ __align__(16) unsigned lds[16 * 56];
    const int j = threadIdx.x;
    const int q = j & 3, u = j >> 2, H = q & 1, gA = (q >> 1) * 2;
    const int hoff = H * 112;                       // byte offset of my half in a record
    const int hidx = (u < 50) ? u : 56 + (u - 50);  // f16 index of h[u] in padded record
    const int kk = j - 448;
    const int pidx = (kk < 25) ? kk : kk + 3;       // u32 index of packed pair kk
    const float s_ = (q == 2) ? 2.f : 1.f;          // lane q==2: tanh = 2*sig(2x)-1
    const float addc_ = (q == 2) ? -1.f : 0.f;

    if (blockIdx.x == 0) {
        // ---------------- B0: layer-0 scan (round-8 verbatim) ----------------
        h2 wA[25], wB[25];
        float xa = 0.f, xb = 0.f, c0 = 0.f;
        if (j < 400) {
            int r0 = gA * 100 + u;
            ldw(wA, Whh0 + r0 * 100 + 50 * H);
            ldw(wB, Whh0 + (r0 + 100) * 100 + 50 * H);
            xa = (float)x0p[j];
            xb = (float)x0p[400 + j];
        }
        if (j < 224) lds[j] = 0u;  // h0(-1)=0, both buffers
        __syncthreads();

        for (int t = 0; t < T_STEPS; t += 2) {
            B0TICK(t, xa, 0);
            B0TICK(t + 1, xb, 1);
        }
        if (j >= 448) {  // publish h0(T-1) (sits in buffer 0) + final flag
            if (kk < 50) AST(&h0seq[(size_t)(T_STEPS - 1) * 50 + kk], lds[pidx]);
            if (kk == 0) ASTR(&flags[0], (unsigned)T_STEPS);
        }
    } else if (blockIdx.x == 1) {
        // ---------------- Bz: z1 streaming GEMM, 16-tick tiles ----------------
        h2 wA[25], wB[25];
        float bz = 0.f;
        if (j < 400) {
            int r0 = gA * 100 + u;
            ldw(wA, Wih1 + r0 * 100 + 50 * H);
            ldw(wB, Wih1 + (r0 + 100) * 100 + 50 * H);
            int ro = q * 100 + u;  // my OWN gate row (post H-select)
            bz = bih1[ro] + bhh1[ro];
        }
        for (int idx = j; idx < 16 * 56; idx += 512) lds[idx] = 0u;
        __syncthreads();

        unsigned fcache = 0, bpc = 0;
        for (int tau = 0; tau < 2048; ++tau) {
            const int t0 = tau * 16;
            // h0 availability: flags[0]=T means h0seq ticks <= T-1 done; need t0+15
            while (fcache < (unsigned)(t0 + 16)) {
                fcache = ALD(&flags[0]);
                if (fcache < (unsigned)(t0 + 16)) __builtin_amdgcn_s_sleep(8);
            }
            // ring backpressure: slots (t0..t0+15)&RMASK held ticks t0+tt-16384,
            // last read by B2 at its tick t0+tt-16386. flags[2]=B2 T+1 (per 256).
            int lim = t0 + 32 - (RMASK + 1);
            if (lim > 0) {
                while ((int)bpc < lim) {
                    bpc = ALD(&flags[2]);
                    if ((int)bpc < lim) __builtin_amdgcn_s_sleep(8);
                }
            }
            CFENCE();
            // stage tile: 800 packed u32 -> 16 padded LDS records
            for (int g = j; g < 800; g += 512) {
                int tt = g / 50, k = g % 50;
                lds[tt * 56 + ((k < 25) ? k : k + 3)] = ALD(&h0seq[(size_t)t0 * 50 + g]);
            }
            __syncthreads();
            if (j < 400) {
                for (int tt = 0; tt < 16; ++tt) {
                    float2 p = mv25(wA, wB, (const char*)(lds + tt * 56) + hoff);
                    float pA = p.x + qperm<0xB1>(p.x);
                    float pB = p.y + qperm<0xB1>(p.y);
                    AST(&z1ring[(size_t)((t0 + tt) & RMASK) * 400 + j], (H ? pB : pA) + bz);
                }
            }
            __syncthreads();  // per-wave vmcnt(0) drain -> all z stores complete
            if (j == 0) ASTR(&flags[1], (unsigned)(tau + 1));
        }
    } else {
        // ---------------- B2: layer-1 scan ----------------
        h2 wA[25], wB[25];
        float za = 0.f, zb = 0.f, c1 = 0.f;
        unsigned zdc = 0;
        if (j < 400) {
            int r0 = gA * 100 + u;
            ldw(wA, Whh1 + r0 * 100 + 50 * H);
            ldw(wB, Whh1 + (r0 + 100) * 100 + 50 * H);
        }
        if (j < 224) lds[j] = 0u;  // h1(-1)=0, both buffers
        __syncthreads();
        if (j == 448) {  // wait for z tile 0 (ticks 0..15)
            while ((zdc = ALD(&flags[1])) < 1u) __builtin_amdgcn_s_sleep(8);
            CFENCE();
        }
        __syncthreads();
        if (j < 400) {
            za = ALD(&z1ring[j]);        // z(0)
            zb = ALD(&z1ring[400 + j]);  // z(1)
        }

        for (int t = 0; t < T_STEPS; t += 2) {
            B2TICK(t, za, 0);      // use z(t); prefetch za=z(t+2)
            B2TICK(t + 1, zb, 1);  // use z(t+1); prefetch zb=z(t+3)
        }
    }
}

// ---------------- C: outputs[t][d] = h1s[t] . W_out[d] + b_out[d] ----------------
__global__ __launch_bounds__(320) void k_out(const float* __restrict__ h1s,
                                             const float* __restrict__ Wout,
                                             const float* __restrict__ bout,
                                             float* __restrict__ out) {
    __shared__ float hs[32 * 100];
    int t0 = blockIdx.x * 32;
    for (int idx = threadIdx.x; idx < 3200; idx += 320) hs[idx] = h1s[(size_t)t0 * 100 + idx];
    __syncthreads();
    int d = threadIdx.x;
    if (d < 300) {
        float acc[32];
#pragma unroll
        for (int i = 0; i < 32; i++) acc[i] = 0.f;
        const float4* w4 = (const float4*)(Wout + d * 100);
        const float4* h4 = (const float4*)hs;
        for (int j4 = 0; j4 < 25; j4++) {
            float4 w = w4[j4];
#pragma unroll
            for (int ti = 0; ti < 32; ti++) {
                float4 h = h4[ti * 25 + j4];
                acc[ti] += w.x * h.x + w.y * h.y + w.z * h.z + w.w * h.w;
            }
        }
        float bb = bout[d];
#pragma unroll
        for (int ti = 0; ti < 32; ti++) out[(size_t)(t0 + ti) * 300 + d] = acc[ti] + bb;
    }
}

extern "C" void kernel_launch(void* const* d_in, const int* in_sizes, int n_in,
                              void* d_out, int out_size, void* d_ws, size_t ws_size,
                              hipStream_t stream) {
    const float* inputs = (const float*)d_in[0];
    const float* W_inp  = (const float*)d_in[1];
    const float* b_inp  = (const float*)d_in[2];
    const float* W_ih0  = (const float*)d_in[3];
    const float* W_hh0  = (const float*)d_in[4];
    const float* b_ih0  = (const float*)d_in[5];
    const float* b_hh0  = (const float*)d_in[6];
    const float* W_ih1  = (const float*)d_in[7];
    const float* W_hh1  = (const float*)d_in[8];
    const float* b_ih1  = (const float*)d_in[9];
    const float* b_hh1  = (const float*)d_in[10];
    const float* W_out  = (const float*)d_in[11];
    const float* b_out  = (const float*)d_in[12];
    float* out = (float*)d_out;

    char* ws = (char*)d_ws;
    _Float16* x0p = (_Float16*)ws;                    // 32768*400*2 = 26,214,400 B
    float* h1s = (float*)(ws + 26214400);             // 32768*100*4 = 13,107,200 B
    float* Wc  = (float*)(ws + 26214400 + 13107200);  // 400*300*4   =    480,000 B
    float* bc  = Wc + 120000;                         // 400*4 B

    // out-scratch region [0, OUT_BASE*4): fully overwritten by k_out afterwards.
    //   z1ring: 16384*400*4 = 26,214,400 B  @ 0
    //   h0seq : 32768*50*4  =  6,553,600 B  @ 26,214,400
    //   flags : 3 u32                       @ 32,768,000   (all < 39,321,600)
    float*    z1ring = out;
    unsigned* h0seq  = (unsigned*)((char*)out + 26214400);
    unsigned* flagsp = (unsigned*)((char*)out + 32768000);
    float*    outTail = out + OUT_BASE;

    hipMemsetAsync(flagsp, 0, 16, stream);
    k_precomp<<<471, 256, 0, stream>>>(W_inp, b_inp, W_ih0, b_ih0, b_hh0, Wc, bc);
    k_xproj<<<1024, 512, 0, stream>>>(inputs, Wc, bc, x0p);

    void* args[] = {(void*)&x0p, (void*)&W_hh0, (void*)&W_ih1, (void*)&W_hh1,
                    (void*)&b_ih1, (void*)&b_hh1, (void*)&h1s, (void*)&outTail,
                    (void*)&h0seq, (void*)&z1ring, (void*)&flagsp};
    hipLaunchCooperativeKernel((void*)k_scan3, dim3(3), dim3(512), args, 0, stream);

    k_out<<<1024, 320, 0, stream>>>(h1s, W_out, b_out, out);
}